// Round 7
// baseline (115.655 us; speedup 1.0000x reference)
//
#include <hip/hip_runtime.h>
#include <hip/hip_bf16.h>
#include <math.h>

#define DIM 768
#define NH 12
#define DH 64
#define SEQ 2048
#define BATCH 2
#define TOK (BATCH*SEQ)   // 4096
#define QKVN (3*DIM)      // 2304

typedef __attribute__((ext_vector_type(8))) short bf16x8;
typedef __attribute__((ext_vector_type(4))) float f32x4;
typedef __attribute__((ext_vector_type(2))) unsigned int u32x2;
typedef unsigned short u16;

#define VM0 asm volatile("s_waitcnt vmcnt(0)" ::: "memory")
#define VM2 asm volatile("s_waitcnt vmcnt(2)" ::: "memory")
#define VM4 asm volatile("s_waitcnt vmcnt(4)" ::: "memory")
#define LGKM0 asm volatile("s_waitcnt lgkmcnt(0)" ::: "memory")
#define BAR() __builtin_amdgcn_s_barrier()

__device__ inline u16 f2bf(float f) {
  union { float f; unsigned u; } v; v.f = f;
  unsigned u = v.u;
  u += 0x7fffu + ((u >> 16) & 1u);   // round-to-nearest-even
  return (u16)(u >> 16);
}

__device__ inline int pkbf(float a, float b) {   // packed bf16 pair (RNE)
  __hip_bfloat162 h = __float22bfloat162_rn(make_float2(a, b));
  int r; __builtin_memcpy(&r, &h, 4); return r;
}

// One launch converts x, qkv_w, proj_w.
__global__ void conv_all(const float* __restrict__ a, u16* __restrict__ ao, int na4,
                         const float* __restrict__ b, u16* __restrict__ bo, int nb4,
                         const float* __restrict__ c, u16* __restrict__ co, int nc4) {
  int i4 = blockIdx.x * blockDim.x + threadIdx.x;
  const float* src; u16* dst; int off;
  if (i4 < na4)            { src = a; dst = ao; off = i4; }
  else if (i4 < na4 + nb4) { src = b; dst = bo; off = i4 - na4; }
  else if (i4 < na4 + nb4 + nc4) { src = c; dst = co; off = i4 - na4 - nb4; }
  else return;
  float4 v = ((const float4*)src)[off];
  ushort4 o;
  o.x = f2bf(v.x); o.y = f2bf(v.y); o.z = f2bf(v.z); o.w = f2bf(v.w);
  ((ushort4*)dst)[off] = o;
}

// cos/sin table: tab[t*32+p], p<30 real, p>=30 -> (1,0) passthrough.
__global__ void rope_tab(const float* __restrict__ pos, float2* __restrict__ tab) {
  int e = blockIdx.x * blockDim.x + threadIdx.x;   // 4096*32
  int t = e >> 5, p = e & 31;
  float cs = 1.f, sn = 0.f;
  if (p < 30) {
    int axis = p / 10, fi = p % 10;
    float freq = exp2f(-(float)fi * 1.3287712379549449f); // log2(10000)/10
    float ang = pos[t * 3 + axis] * freq;
    cs = cosf(ang); sn = sinf(ang);
  }
  tab[e] = make_float2(cs, sn);
}

#define GLL(g, s) __builtin_amdgcn_global_load_lds((const __attribute__((address_space(1))) void*)(g), (__attribute__((address_space(3))) void*)(s), 16, 0, 0)

// Proj GEMM: C = A * W^T + bias, bf16 in, fp32 out.
// Double-buffered LDS + counted vmcnt (T4): prefetch stays in flight across
// the barrier; only the last iter drains to 0.
__global__ __launch_bounds__(256) void gemm128(
    const u16* __restrict__ A, const u16* __restrict__ W,
    float* __restrict__ C, const float* __restrict__ bias,
    int M, int Nn, int K)
{
  __shared__ u16 As[2][128 * 32];
  __shared__ u16 Bs[2][128 * 32];
  const int t = threadIdx.x;
  const int w = t >> 6, l = t & 63;
  const int lr = l & 15, lg = l >> 4;
  const int wr = w >> 1, wc = w & 1;
  const int m0 = blockIdx.x * 128;
  const int n0 = blockIdx.y * 128;
  f32x4 acc[4][4] = {};
  const int srow = t >> 2;
  const int scol = (t & 3) * 8;
  const u16* aSrc = A + (size_t)(m0 + srow) * K + scol;
  const u16* bSrc = W + (size_t)(n0 + srow) * K + scol;
  const size_t rstep = (size_t)64 * K;
  const int NT = K / 32;

  GLL(aSrc,         &As[0][w * 512]);
  GLL(aSrc + rstep, &As[0][w * 512 + 2048]);
  GLL(bSrc,         &Bs[0][w * 512]);
  GLL(bSrc + rstep, &Bs[0][w * 512 + 2048]);

  for (int kt = 0; kt < NT; ++kt) {
    const int cur = kt & 1;
    if (kt + 1 < NT) {
      const int k0 = (kt + 1) * 32;
      u16* aD = &As[cur ^ 1][w * 512];
      u16* bD = &Bs[cur ^ 1][w * 512];
      GLL(aSrc + k0,         aD);
      GLL(aSrc + rstep + k0, aD + 2048);
      GLL(bSrc + k0,         bD);
      GLL(bSrc + rstep + k0, bD + 2048);
      VM4;
    } else {
      VM0;
    }
    BAR();
    bf16x8 af[4], bff[4];
#pragma unroll
    for (int mi = 0; mi < 4; ++mi)
      af[mi] = *(const bf16x8*)(&As[cur][0] + (wr * 64 + mi * 16 + lr) * 32 + lg * 8);
#pragma unroll
    for (int ni = 0; ni < 4; ++ni)
      bff[ni] = *(const bf16x8*)(&Bs[cur][0] + (wc * 64 + ni * 16 + lr) * 32 + lg * 8);
#pragma unroll
    for (int mi = 0; mi < 4; ++mi)
#pragma unroll
      for (int ni = 0; ni < 4; ++ni)
        acc[mi][ni] = __builtin_amdgcn_mfma_f32_16x16x32_bf16(af[mi], bff[ni], acc[mi][ni], 0, 0, 0);
    LGKM0;
    BAR();
  }

#pragma unroll
  for (int mi = 0; mi < 4; ++mi)
#pragma unroll
    for (int ni = 0; ni < 4; ++ni)
#pragma unroll
      for (int r = 0; r < 4; ++r) {
        int row = m0 + wr * 64 + mi * 16 + lg * 4 + r;
        int col = n0 + wc * 64 + ni * 16 + lr;
        C[(size_t)row * Nn + col] = acc[mi][ni][r] + bias[col];
      }
}

// QKV GEMM with fused RMSNorm + RoPE + layout epilogue, same T4 pipeline.
__global__ __launch_bounds__(256) void gemm_qkv(
    const u16* __restrict__ A, const u16* __restrict__ W,
    const float* __restrict__ qn_w, const float* __restrict__ kn_w,
    const float2* __restrict__ tab,
    u16* __restrict__ Qb, u16* __restrict__ Kb, u16* __restrict__ Vtb)
{
  __shared__ u16 As[2][128 * 32];
  __shared__ u16 Bs[2][128 * 32];
  const int K = DIM;
  const int t = threadIdx.x;
  const int w = t >> 6, l = t & 63;
  const int lr = l & 15, lg = l >> 4;
  const int wr = w >> 1, wc = w & 1;
  const int m0 = blockIdx.x * 128;
  const int n0 = blockIdx.y * 128;
  f32x4 acc[4][4] = {};
  const int srow = t >> 2;
  const int scol = (t & 3) * 8;
  const u16* aSrc = A + (size_t)(m0 + srow) * K + scol;
  const u16* bSrc = W + (size_t)(n0 + srow) * K + scol;
  const size_t rstep = (size_t)64 * K;
  const int NT = K / 32;

  GLL(aSrc,         &As[0][w * 512]);
  GLL(aSrc + rstep, &As[0][w * 512 + 2048]);
  GLL(bSrc,         &Bs[0][w * 512]);
  GLL(bSrc + rstep, &Bs[0][w * 512 + 2048]);

  for (int kt = 0; kt < NT; ++kt) {
    const int cur = kt & 1;
    if (kt + 1 < NT) {
      const int k0 = (kt + 1) * 32;
      u16* aD = &As[cur ^ 1][w * 512];
      u16* bD = &Bs[cur ^ 1][w * 512];
      GLL(aSrc + k0,         aD);
      GLL(aSrc + rstep + k0, aD + 2048);
      GLL(bSrc + k0,         bD);
      GLL(bSrc + rstep + k0, bD + 2048);
      VM4;
    } else {
      VM0;
    }
    BAR();
    bf16x8 af[4], bff[4];
#pragma unroll
    for (int mi = 0; mi < 4; ++mi)
      af[mi] = *(const bf16x8*)(&As[cur][0] + (wr * 64 + mi * 16 + lr) * 32 + lg * 8);
#pragma unroll
    for (int ni = 0; ni < 4; ++ni)
      bff[ni] = *(const bf16x8*)(&Bs[cur][0] + (wc * 64 + ni * 16 + lr) * 32 + lg * 8);
#pragma unroll
    for (int mi = 0; mi < 4; ++mi)
#pragma unroll
      for (int ni = 0; ni < 4; ++ni)
        acc[mi][ni] = __builtin_amdgcn_mfma_f32_16x16x32_bf16(af[mi], bff[ni], acc[mi][ni], 0, 0, 0);
    LGKM0;
    BAR();
  }

  // ---- fused epilogue ----
  const int chunk = (n0 >> 6) + wc;        // 0..35 over [3 types][12 heads]
  const int tt = chunk / 12;               // 0=q 1=k 2=v
  const int h  = chunk % 12;
  const int bB = m0 >> 11;                 // batch (block-const)
  const int bh = bB * NH + h;

  if (tt == 2) {
    // V: transposed (B,H,DH,N)
#pragma unroll
    for (int mi = 0; mi < 4; ++mi) {
      const int nbase = (m0 + wr * 64 + mi * 16 + lg * 4) & 2047;
#pragma unroll
      for (int ni = 0; ni < 4; ++ni) {
        const int d = ni * 16 + lr;
        ushort4 o;
        o.x = f2bf(acc[mi][ni][0]); o.y = f2bf(acc[mi][ni][1]);
        o.z = f2bf(acc[mi][ni][2]); o.w = f2bf(acc[mi][ni][3]);
        *(ushort4*)(Vtb + ((size_t)bh * DH + d) * SEQ + nbase) = o;
      }
    }
  } else {
    const float* wv = (tt == 0 ? qn_w : kn_w);
    const float qs = (tt == 0 ? 0.125f * 1.4426950408889634f : 1.f);
    float wgt[4];
#pragma unroll
    for (int ni = 0; ni < 4; ++ni) wgt[ni] = wv[ni * 16 + lr];
    u16* outp = (tt == 0 ? Qb : Kb) + (size_t)bh * SEQ * DH;
#pragma unroll
    for (int mi = 0; mi < 4; ++mi) {
#pragma unroll
      for (int r = 0; r < 4; ++r) {
        float ss = 0.f;
#pragma unroll
        for (int ni = 0; ni < 4; ++ni) ss += acc[mi][ni][r] * acc[mi][ni][r];
        ss += __shfl_xor(ss, 1, 64);
        ss += __shfl_xor(ss, 2, 64);
        ss += __shfl_xor(ss, 4, 64);
        ss += __shfl_xor(ss, 8, 64);
        const float rms = rsqrtf(ss * (1.f / 64.f) + 1e-6f);
        const int trow = m0 + wr * 64 + mi * 16 + lg * 4 + r;
        const float2* tl = tab + trow * 32;
        u16* rowp = outp + (size_t)(trow & 2047) * DH;
#pragma unroll
        for (int ni = 0; ni < 4; ++ni) {
          const int d = ni * 16 + lr;
          float v = acc[mi][ni][r] * rms * wgt[ni];
          float vp = __shfl_xor(v, 1, 64);
          float2 cssn = tl[ni * 8 + (lr >> 1)];
          float sgn = (d & 1) ? cssn.y : -cssn.y;
          rowp[d] = f2bf((v * cssn.x + vp * sgn) * qs);
        }
      }
    }
  }
}

// Flash attention, swapped-operand, static-shift softmax (exact).
// 8 waves = 4 q-groups x 2 KV-halves; K pair-dbuf + single V buffer (48KB).
// T4 counted-vmcnt schedule: per-wave VMEM queue [K(i)2, V(i)2, K(i+1)2]:
//   QK barrier: vmcnt(4)  (K(i) landed, prefetches in flight)
//   alpha:      vmcnt(2)  (V(i) landed)
//   beta:       plain     (Vs write-after-read only)
__global__ __launch_bounds__(512, 6) void attn(
    const u16* __restrict__ Qb, const u16* __restrict__ Kb,
    const u16* __restrict__ Vtb, u16* __restrict__ Ob)
{
  __shared__ u16 Ks[2][2][64 * 64];   // [pair dbuf][half]
  __shared__ u16 Vs[2][64 * 64];      // [half]
  const int tid = threadIdx.x;
  const int w = tid >> 6, l = tid & 63;
  const int lr = l & 15, lg = l >> 4;
  const int qg = w & 3, half = w >> 2;
  const int wg = blockIdx.x;
  const int swz = (wg & 7) * 96 + (wg >> 3);   // bijective, 768 % 8 == 0
  const int bh = swz >> 5;
  const int q0 = (swz & 31) * 64;
  const u16* Qp = Qb + (size_t)bh * SEQ * DH;
  const u16* Kp = Kb + (size_t)bh * SEQ * DH;
  const u16* Vp = Vtb + (size_t)bh * DH * SEQ;

  const int qrow = q0 + qg * 16 + lr;
  const bf16x8 bq0 = *(const bf16x8*)(Qp + (size_t)qrow * DH + 8 * lg);
  const bf16x8 bq1 = *(const bf16x8*)(Qp + (size_t)qrow * DH + 32 + 8 * lg);

  const int srow = tid >> 3;
  const int sc16 = (tid & 7) ^ (srow & 7);
  const u16* kSrc = Kp + (size_t)srow * DH + sc16 * 8;    // + kt*4096
  const u16* vSrc = Vp + (size_t)srow * SEQ + sc16 * 8;   // + kt*64

  const int frow = (lr & 3) | ((lr & 4) << 1) | ((lr & 8) >> 1);
  const int ksw = frow & 7;
  const int vsw = lr & 7;

  f32x4 oacc[4] = {};
  float lsum = 0.f;

  // prologue: K(0), V(0)
  GLL(kSrc,        &Ks[0][0][w * 512]);
  GLL(kSrc + 4096, &Ks[0][1][w * 512]);
  GLL(vSrc,        &Vs[0][w * 512]);
  GLL(vSrc + 64,   &Vs[1][w * 512]);

  for (int i = 0; i < 16; ++i) {
    const int p = i & 1;
    if (i + 1 < 16) {   // K prefetch for pair i+1
      const size_t ko = (size_t)(2 * i + 2) * 4096;
      GLL(kSrc + ko,        &Ks[p ^ 1][0][w * 512]);
      GLL(kSrc + ko + 4096, &Ks[p ^ 1][1][w * 512]);
      VM4;
    } else {
      VM2;
    }
    BAR();   // K(i) staged everywhere
    const u16* Kt = &Ks[p][half][0];
    const u16* Vt = &Vs[half][0];

    f32x4 pacc[4] = {};
    __builtin_amdgcn_s_setprio(1);
#pragma unroll
    for (int c = 0; c < 4; ++c) {
      const int rbase = (16 * c + frow) * 64;
      bf16x8 ka = *(const bf16x8*)(Kt + rbase + ((lg ^ ksw) * 8));
      bf16x8 kb = *(const bf16x8*)(Kt + rbase + (((4 + lg) ^ ksw) * 8));
      pacc[c] = __builtin_amdgcn_mfma_f32_16x16x32_bf16(ka, bq0, pacc[c], 0, 0, 0);
      pacc[c] = __builtin_amdgcn_mfma_f32_16x16x32_bf16(kb, bq1, pacc[c], 0, 0, 0);
    }
    __builtin_amdgcn_s_setprio(0);
    float pp[4][4];
#pragma unroll
    for (int c = 0; c < 4; ++c)
#pragma unroll
      for (int r = 0; r < 4; ++r) {
        float pv = __builtin_amdgcn_exp2f(pacc[c][r] - 12.f);
        pp[c][r] = pv;
        lsum += pv;
      }

    if (i + 1 < 16) { VM2; } else { VM0; }
    LGKM0;
    BAR();   // alpha: V(i) staged; K reads of this iter complete

    // PV from Vs[half]
#pragma unroll
    for (int g = 0; g < 2; ++g) {
      const int clo = 2 * g, chi = 2 * g + 1;
      unsigned x01 = (unsigned)pkbf(pp[clo][0], pp[clo][1]);
      unsigned x23 = (unsigned)pkbf(pp[clo][2], pp[clo][3]);
      unsigned y01 = (unsigned)pkbf(pp[chi][0], pp[chi][1]);
      unsigned y23 = (unsigned)pkbf(pp[chi][2], pp[chi][3]);
      u32x2 r0 = __builtin_amdgcn_permlane32_swap(x01, y01, false, false);
      u32x2 r1 = __builtin_amdgcn_permlane32_swap(x23, y23, false, false);
      union { unsigned d[4]; bf16x8 v; } pu;
      pu.d[0] = r0[0]; pu.d[1] = r1[0]; pu.d[2] = r0[1]; pu.d[3] = r1[1];
      __builtin_amdgcn_s_setprio(1);
#pragma unroll
      for (int dt = 0; dt < 4; ++dt) {
        bf16x8 va = *(const bf16x8*)(Vt + (16 * dt + lr) * 64 + (((4 * g + lg) ^ vsw) * 8));
        oacc[dt] = __builtin_amdgcn_mfma_f32_16x16x32_bf16(va, pu.v, oacc[dt], 0, 0, 0);
      }
      __builtin_amdgcn_s_setprio(0);
    }

    LGKM0;
    BAR();   // beta: all waves done reading Vs

    if (i + 1 < 16) {   // V stage for pair i+1 (lands during next QK+softmax)
      const size_t vo = (size_t)(2 * i + 2) * 64;
      GLL(vSrc + vo,      &Vs[0][w * 512]);
      GLL(vSrc + vo + 64, &Vs[1][w * 512]);
    }
  }

  // combine halves (static shift => additive partials). All VMEM drained.
  float* scr = (float*)&Ks[0][0][0];
  const int sid = qg * 64 + l;
  if (half == 1) {
#pragma unroll
    for (int dt = 0; dt < 4; ++dt)
#pragma unroll
      for (int r = 0; r < 4; ++r)
        scr[sid * 17 + dt * 4 + r] = oacc[dt][r];
    scr[sid * 17 + 16] = lsum;
  }
  __syncthreads();
  if (half == 1) return;
#pragma unroll
  for (int dt = 0; dt < 4; ++dt)
#pragma unroll
    for (int r = 0; r < 4; ++r)
      oacc[dt][r] += scr[sid * 17 + dt * 4 + r];
  lsum += scr[sid * 17 + 16];

  lsum += __shfl_xor(lsum, 16, 64);
  lsum += __shfl_xor(lsum, 32, 64);
  const float inv = 1.f / lsum;
  const int b = bh / NH, h = bh % NH;
  const int q = q0 + qg * 16 + lr;
  size_t obase = (size_t)(b * SEQ + q) * DIM + h * DH + 4 * lg;
#pragma unroll
  for (int dt = 0; dt < 4; ++dt) {
    ushort4 o;
    o.x = f2bf(oacc[dt][0] * inv);
    o.y = f2bf(oacc[dt][1] * inv);
    o.z = f2bf(oacc[dt][2] * inv);
    o.w = f2bf(oacc[dt][3] * inv);
    *(ushort4*)(Ob + obase + 16 * dt) = o;
  }
}

extern "C" void kernel_launch(void* const* d_in, const int* in_sizes, int n_in,
                              void* d_out, int out_size, void* d_ws, size_t ws_size,
                              hipStream_t stream) {
  const float* x      = (const float*)d_in[0];
  const float* pos    = (const float*)d_in[1];
  const float* qkv_w  = (const float*)d_in[2];
  const float* proj_w = (const float*)d_in[3];
  const float* proj_b = (const float*)d_in[4];
  const float* qn_w   = (const float*)d_in[5];
  const float* kn_w   = (const float*)d_in[6];
  char* ws = (char*)d_ws;
  u16*    xb    = (u16*)(ws + 0);          // 6291456
  u16*    wqkv  = (u16*)(ws + 6291456);    // 3538944
  u16*    wproj = (u16*)(ws + 9830400);    // 1179648
  float2* tab   = (float2*)(ws + 11010048);// 1048576
  u16*    Qb    = (u16*)(ws + 12058624);   // 6291456
  u16*    Kb    = (u16*)(ws + 18350080);   // 6291456
  u16*    Vtb   = (u16*)(ws + 24641536);   // 6291456
  u16*    Ob    = (u16*)(ws + 30932992);   // 6291456 -> total 37224448
  float* out = (float*)d_out;

  const int na4 = TOK * DIM / 4, nb4 = QKVN * DIM / 4, nc4 = DIM * DIM / 4;
  conv_all<<<(na4 + nb4 + nc4 + 255) / 256, 256, 0, stream>>>(
      x, xb, na4, qkv_w, wqkv, nb4, proj_w, wproj, nc4);

  rope_tab<<<TOK * 32 / 256, 256, 0, stream>>>(pos, tab);

  dim3 g1(TOK / 128, QKVN / 128);
  gemm_qkv<<<g1, 256, 0, stream>>>(xb, wqkv, qn_w, kn_w, tab, Qb, Kb, Vtb);

  attn<<<SEQ / 64 * BATCH * NH, 512, 0, stream>>>(Qb, Kb, Vtb, Ob);

  dim3 g3(TOK / 128, DIM / 128);
  gemm128<<<g3, 256, 0, stream>>>(Ob, wproj, out, proj_b, TOK, DIM, DIM);
}

// Round 8
// 94.251 us; speedup vs baseline: 1.2271x; 1.2271x over previous
//
#include <hip/hip_runtime.h>
#include <hip/hip_bf16.h>
#include <math.h>

#define DIM 768
#define NH 12
#define DH 64
#define SEQ 2048
#define BATCH 2
#define TOK (BATCH*SEQ)   // 4096
#define QKVN (3*DIM)      // 2304

typedef __attribute__((ext_vector_type(8))) short bf16x8;
typedef __attribute__((ext_vector_type(4))) float f32x4;
typedef __attribute__((ext_vector_type(2))) unsigned int u32x2;
typedef unsigned short u16;

#define VM0 asm volatile("s_waitcnt vmcnt(0)" ::: "memory")
#define VM2 asm volatile("s_waitcnt vmcnt(2)" ::: "memory")
#define VM4 asm volatile("s_waitcnt vmcnt(4)" ::: "memory")
#define LGKM0 asm volatile("s_waitcnt lgkmcnt(0)" ::: "memory")
#define BAR() __builtin_amdgcn_s_barrier()

__device__ inline u16 f2bf(float f) {
  union { float f; unsigned u; } v; v.f = f;
  unsigned u = v.u;
  u += 0x7fffu + ((u >> 16) & 1u);   // round-to-nearest-even
  return (u16)(u >> 16);
}

__device__ inline int pkbf(float a, float b) {   // packed bf16 pair (RNE)
  __hip_bfloat162 h = __float22bfloat162_rn(make_float2(a, b));
  int r; __builtin_memcpy(&r, &h, 4); return r;
}

// One launch: convert x, qkv_w, proj_w to bf16 AND build the rope cos/sin table.
__global__ void conv_all(const float* __restrict__ a, u16* __restrict__ ao, int na4,
                         const float* __restrict__ b, u16* __restrict__ bo, int nb4,
                         const float* __restrict__ c, u16* __restrict__ co, int nc4,
                         const float* __restrict__ pos, float2* __restrict__ tab) {
  int i4 = blockIdx.x * blockDim.x + threadIdx.x;
  const int nconv = na4 + nb4 + nc4;
  if (i4 < nconv) {
    const float* src; u16* dst; int off;
    if (i4 < na4)            { src = a; dst = ao; off = i4; }
    else if (i4 < na4 + nb4) { src = b; dst = bo; off = i4 - na4; }
    else                     { src = c; dst = co; off = i4 - na4 - nb4; }
    float4 v = ((const float4*)src)[off];
    ushort4 o;
    o.x = f2bf(v.x); o.y = f2bf(v.y); o.z = f2bf(v.z); o.w = f2bf(v.w);
    ((ushort4*)dst)[off] = o;
    return;
  }
  int e = i4 - nconv;                 // rope table: 4096*32 entries
  if (e >= TOK * 32) return;
  int t = e >> 5, p = e & 31;
  float cs = 1.f, sn = 0.f;
  if (p < 30) {
    int axis = p / 10, fi = p % 10;
    float freq = exp2f(-(float)fi * 1.3287712379549449f); // log2(10000)/10
    float ang = pos[t * 3 + axis] * freq;
    cs = cosf(ang); sn = sinf(ang);
  }
  tab[e] = make_float2(cs, sn);
}

#define GLL(g, s) __builtin_amdgcn_global_load_lds((const __attribute__((address_space(1))) void*)(g), (__attribute__((address_space(3))) void*)(s), 16, 0, 0)

// Proj GEMM: C = A * W^T + bias, bf16 in, fp32 out. 64x64 tile, 4 waves of
// 32x32 -> grid 64x12=768 blocks (3/CU, 12 waves/CU) for latency hiding.
__global__ __launch_bounds__(256, 6) void gemm64(
    const u16* __restrict__ A, const u16* __restrict__ W,
    float* __restrict__ C, const float* __restrict__ bias,
    int M, int Nn, int K)
{
  __shared__ u16 As[2][64 * 32];
  __shared__ u16 Bs[2][64 * 32];
  const int t = threadIdx.x;
  const int w = t >> 6, l = t & 63;
  const int lr = l & 15, lg = l >> 4;
  const int wr = w >> 1, wc = w & 1;
  const int m0 = blockIdx.x * 64;
  const int n0 = blockIdx.y * 64;
  f32x4 acc[2][2] = {};
  const int srow = t >> 2;
  const int scol = (t & 3) * 8;
  const u16* aSrc = A + (size_t)(m0 + srow) * K + scol;
  const u16* bSrc = W + (size_t)(n0 + srow) * K + scol;
  const int NT = K / 32;

  GLL(aSrc, &As[0][w * 512]);
  GLL(bSrc, &Bs[0][w * 512]);

  for (int kt = 0; kt < NT; ++kt) {
    const int cur = kt & 1;
    if (kt + 1 < NT) {
      GLL(aSrc + (kt + 1) * 32, &As[cur ^ 1][w * 512]);
      GLL(bSrc + (kt + 1) * 32, &Bs[cur ^ 1][w * 512]);
      VM2;
    } else {
      VM0;
    }
    BAR();
    bf16x8 af[2], bff[2];
#pragma unroll
    for (int mi = 0; mi < 2; ++mi)
      af[mi] = *(const bf16x8*)(&As[cur][0] + (wr * 32 + mi * 16 + lr) * 32 + lg * 8);
#pragma unroll
    for (int ni = 0; ni < 2; ++ni)
      bff[ni] = *(const bf16x8*)(&Bs[cur][0] + (wc * 32 + ni * 16 + lr) * 32 + lg * 8);
#pragma unroll
    for (int mi = 0; mi < 2; ++mi)
#pragma unroll
      for (int ni = 0; ni < 2; ++ni)
        acc[mi][ni] = __builtin_amdgcn_mfma_f32_16x16x32_bf16(af[mi], bff[ni], acc[mi][ni], 0, 0, 0);
    LGKM0;
    BAR();
  }

#pragma unroll
  for (int mi = 0; mi < 2; ++mi)
#pragma unroll
    for (int ni = 0; ni < 2; ++ni)
#pragma unroll
      for (int r = 0; r < 4; ++r) {
        int row = m0 + wr * 32 + mi * 16 + lg * 4 + r;
        int col = n0 + wc * 32 + ni * 16 + lr;
        C[(size_t)row * Nn + col] = acc[mi][ni][r] + bias[col];
      }
}

// QKV GEMM with fused RMSNorm + RoPE + layout epilogue.
// 512 threads / 8 waves (4M x 2N), wave sub-tile 32x64 => each wave spans one
// full (type,head) 64-col chunk. 18 waves/CU resident vs 9 before.
__global__ __launch_bounds__(512, 4) void gemm_qkv(
    const u16* __restrict__ A, const u16* __restrict__ W,
    const float* __restrict__ qn_w, const float* __restrict__ kn_w,
    const float2* __restrict__ tab,
    u16* __restrict__ Qb, u16* __restrict__ Kb, u16* __restrict__ Vtb)
{
  __shared__ u16 As[2][128 * 32];
  __shared__ u16 Bs[2][128 * 32];
  const int K = DIM;
  const int t = threadIdx.x;
  const int w = t >> 6, l = t & 63;
  const int lr = l & 15, lg = l >> 4;
  const int wr = w >> 1, wc = w & 1;      // 4 x 2 waves
  const int m0 = blockIdx.x * 128;
  const int n0 = blockIdx.y * 128;
  f32x4 acc[2][4] = {};
  const int srow = t >> 2;                // 0..127
  const int scol = (t & 3) * 8;
  const u16* aSrc = A + (size_t)(m0 + srow) * K + scol;
  const u16* bSrc = W + (size_t)(n0 + srow) * K + scol;
  const int NT = K / 32;

  GLL(aSrc, &As[0][w * 512]);
  GLL(bSrc, &Bs[0][w * 512]);

  for (int kt = 0; kt < NT; ++kt) {
    const int cur = kt & 1;
    if (kt + 1 < NT) {
      GLL(aSrc + (kt + 1) * 32, &As[cur ^ 1][w * 512]);
      GLL(bSrc + (kt + 1) * 32, &Bs[cur ^ 1][w * 512]);
      VM2;
    } else {
      VM0;
    }
    BAR();
    bf16x8 af[2], bff[4];
#pragma unroll
    for (int mi = 0; mi < 2; ++mi)
      af[mi] = *(const bf16x8*)(&As[cur][0] + (wr * 32 + mi * 16 + lr) * 32 + lg * 8);
#pragma unroll
    for (int ni = 0; ni < 4; ++ni)
      bff[ni] = *(const bf16x8*)(&Bs[cur][0] + (wc * 64 + ni * 16 + lr) * 32 + lg * 8);
#pragma unroll
    for (int mi = 0; mi < 2; ++mi)
#pragma unroll
      for (int ni = 0; ni < 4; ++ni)
        acc[mi][ni] = __builtin_amdgcn_mfma_f32_16x16x32_bf16(af[mi], bff[ni], acc[mi][ni], 0, 0, 0);
    LGKM0;
    BAR();
  }

  // ---- fused epilogue ----
  const int chunk = (n0 >> 6) + wc;        // 0..35 over [3 types][12 heads]
  const int tt = chunk / 12;               // 0=q 1=k 2=v
  const int h  = chunk % 12;
  const int bB = m0 >> 11;                 // batch (block-const)
  const int bh = bB * NH + h;

  if (tt == 2) {
    // V: transposed (B,H,DH,N)
#pragma unroll
    for (int mi = 0; mi < 2; ++mi) {
      const int nbase = (m0 + wr * 32 + mi * 16 + lg * 4) & 2047;
#pragma unroll
      for (int ni = 0; ni < 4; ++ni) {
        const int d = ni * 16 + lr;
        ushort4 o;
        o.x = f2bf(acc[mi][ni][0]); o.y = f2bf(acc[mi][ni][1]);
        o.z = f2bf(acc[mi][ni][2]); o.w = f2bf(acc[mi][ni][3]);
        *(ushort4*)(Vtb + ((size_t)bh * DH + d) * SEQ + nbase) = o;
      }
    }
  } else {
    const float* wv = (tt == 0 ? qn_w : kn_w);
    const float qs = (tt == 0 ? 0.125f * 1.4426950408889634f : 1.f);
    float wgt[4];
#pragma unroll
    for (int ni = 0; ni < 4; ++ni) wgt[ni] = wv[ni * 16 + lr];
    u16* outp = (tt == 0 ? Qb : Kb) + (size_t)bh * SEQ * DH;
#pragma unroll
    for (int mi = 0; mi < 2; ++mi) {
#pragma unroll
      for (int r = 0; r < 4; ++r) {
        float ss = 0.f;
#pragma unroll
        for (int ni = 0; ni < 4; ++ni) ss += acc[mi][ni][r] * acc[mi][ni][r];
        ss += __shfl_xor(ss, 1, 64);
        ss += __shfl_xor(ss, 2, 64);
        ss += __shfl_xor(ss, 4, 64);
        ss += __shfl_xor(ss, 8, 64);
        const float rms = rsqrtf(ss * (1.f / 64.f) + 1e-6f);
        const int trow = m0 + wr * 32 + mi * 16 + lg * 4 + r;
        const float2* tl = tab + trow * 32;
        u16* rowp = outp + (size_t)(trow & 2047) * DH;
#pragma unroll
        for (int ni = 0; ni < 4; ++ni) {
          const int d = ni * 16 + lr;
          float v = acc[mi][ni][r] * rms * wgt[ni];
          float vp = __shfl_xor(v, 1, 64);
          float2 cssn = tl[ni * 8 + (lr >> 1)];
          float sgn = (d & 1) ? cssn.y : -cssn.y;
          rowp[d] = f2bf((v * cssn.x + vp * sgn) * qs);
        }
      }
    }
  }
}

// Flash attention, swapped-operand, static-shift softmax (exact).
// 8 waves = 4 q-groups x 2 KV-halves; K pair-dbuf + single V buffer (48KB).
// T4 counted-vmcnt schedule.
__global__ __launch_bounds__(512, 6) void attn(
    const u16* __restrict__ Qb, const u16* __restrict__ Kb,
    const u16* __restrict__ Vtb, u16* __restrict__ Ob)
{
  __shared__ u16 Ks[2][2][64 * 64];   // [pair dbuf][half]
  __shared__ u16 Vs[2][64 * 64];      // [half]
  const int tid = threadIdx.x;
  const int w = tid >> 6, l = tid & 63;
  const int lr = l & 15, lg = l >> 4;
  const int qg = w & 3, half = w >> 2;
  const int wg = blockIdx.x;
  const int swz = (wg & 7) * 96 + (wg >> 3);   // bijective, 768 % 8 == 0
  const int bh = swz >> 5;
  const int q0 = (swz & 31) * 64;
  const u16* Qp = Qb + (size_t)bh * SEQ * DH;
  const u16* Kp = Kb + (size_t)bh * SEQ * DH;
  const u16* Vp = Vtb + (size_t)bh * DH * SEQ;

  const int qrow = q0 + qg * 16 + lr;
  const bf16x8 bq0 = *(const bf16x8*)(Qp + (size_t)qrow * DH + 8 * lg);
  const bf16x8 bq1 = *(const bf16x8*)(Qp + (size_t)qrow * DH + 32 + 8 * lg);

  const int srow = tid >> 3;
  const int sc16 = (tid & 7) ^ (srow & 7);
  const u16* kSrc = Kp + (size_t)srow * DH + sc16 * 8;    // + kt*4096
  const u16* vSrc = Vp + (size_t)srow * SEQ + sc16 * 8;   // + kt*64

  const int frow = (lr & 3) | ((lr & 4) << 1) | ((lr & 8) >> 1);
  const int ksw = frow & 7;
  const int vsw = lr & 7;

  f32x4 oacc[4] = {};
  float lsum = 0.f;

  // prologue: K(0), V(0)
  GLL(kSrc,        &Ks[0][0][w * 512]);
  GLL(kSrc + 4096, &Ks[0][1][w * 512]);
  GLL(vSrc,        &Vs[0][w * 512]);
  GLL(vSrc + 64,   &Vs[1][w * 512]);

  for (int i = 0; i < 16; ++i) {
    const int p = i & 1;
    if (i + 1 < 16) {   // K prefetch for pair i+1
      const size_t ko = (size_t)(2 * i + 2) * 4096;
      GLL(kSrc + ko,        &Ks[p ^ 1][0][w * 512]);
      GLL(kSrc + ko + 4096, &Ks[p ^ 1][1][w * 512]);
      VM4;
    } else {
      VM2;
    }
    BAR();   // K(i) staged everywhere
    const u16* Kt = &Ks[p][half][0];
    const u16* Vt = &Vs[half][0];

    f32x4 pacc[4] = {};
    __builtin_amdgcn_s_setprio(1);
#pragma unroll
    for (int c = 0; c < 4; ++c) {
      const int rbase = (16 * c + frow) * 64;
      bf16x8 ka = *(const bf16x8*)(Kt + rbase + ((lg ^ ksw) * 8));
      bf16x8 kb = *(const bf16x8*)(Kt + rbase + (((4 + lg) ^ ksw) * 8));
      pacc[c] = __builtin_amdgcn_mfma_f32_16x16x32_bf16(ka, bq0, pacc[c], 0, 0, 0);
      pacc[c] = __builtin_amdgcn_mfma_f32_16x16x32_bf16(kb, bq1, pacc[c], 0, 0, 0);
    }
    __builtin_amdgcn_s_setprio(0);
    float pp[4][4];
#pragma unroll
    for (int c = 0; c < 4; ++c)
#pragma unroll
      for (int r = 0; r < 4; ++r) {
        float pv = __builtin_amdgcn_exp2f(pacc[c][r] - 12.f);
        pp[c][r] = pv;
        lsum += pv;
      }

    if (i + 1 < 16) { VM2; } else { VM0; }
    LGKM0;
    BAR();   // alpha: V(i) staged; K reads of this iter complete

    // PV from Vs[half]
#pragma unroll
    for (int g = 0; g < 2; ++g) {
      const int clo = 2 * g, chi = 2 * g + 1;
      unsigned x01 = (unsigned)pkbf(pp[clo][0], pp[clo][1]);
      unsigned x23 = (unsigned)pkbf(pp[clo][2], pp[clo][3]);
      unsigned y01 = (unsigned)pkbf(pp[chi][0], pp[chi][1]);
      unsigned y23 = (unsigned)pkbf(pp[chi][2], pp[chi][3]);
      u32x2 r0 = __builtin_amdgcn_permlane32_swap(x01, y01, false, false);
      u32x2 r1 = __builtin_amdgcn_permlane32_swap(x23, y23, false, false);
      union { unsigned d[4]; bf16x8 v; } pu;
      pu.d[0] = r0[0]; pu.d[1] = r1[0]; pu.d[2] = r0[1]; pu.d[3] = r1[1];
      __builtin_amdgcn_s_setprio(1);
#pragma unroll
      for (int dt = 0; dt < 4; ++dt) {
        bf16x8 va = *(const bf16x8*)(Vt + (16 * dt + lr) * 64 + (((4 * g + lg) ^ vsw) * 8));
        oacc[dt] = __builtin_amdgcn_mfma_f32_16x16x32_bf16(va, pu.v, oacc[dt], 0, 0, 0);
      }
      __builtin_amdgcn_s_setprio(0);
    }

    LGKM0;
    BAR();   // beta: all waves done reading Vs

    if (i + 1 < 16) {   // V stage for pair i+1 (lands during next QK+softmax)
      const size_t vo = (size_t)(2 * i + 2) * 64;
      GLL(vSrc + vo,      &Vs[0][w * 512]);
      GLL(vSrc + vo + 64, &Vs[1][w * 512]);
    }
  }

  // combine halves (static shift => additive partials). All VMEM drained.
  float* scr = (float*)&Ks[0][0][0];
  const int sid = qg * 64 + l;
  if (half == 1) {
#pragma unroll
    for (int dt = 0; dt < 4; ++dt)
#pragma unroll
      for (int r = 0; r < 4; ++r)
        scr[sid * 17 + dt * 4 + r] = oacc[dt][r];
    scr[sid * 17 + 16] = lsum;
  }
  __syncthreads();
  if (half == 1) return;
#pragma unroll
  for (int dt = 0; dt < 4; ++dt)
#pragma unroll
    for (int r = 0; r < 4; ++r)
      oacc[dt][r] += scr[sid * 17 + dt * 4 + r];
  lsum += scr[sid * 17 + 16];

  lsum += __shfl_xor(lsum, 16, 64);
  lsum += __shfl_xor(lsum, 32, 64);
  const float inv = 1.f / lsum;
  const int b = bh / NH, h = bh % NH;
  const int q = q0 + qg * 16 + lr;
  size_t obase = (size_t)(b * SEQ + q) * DIM + h * DH + 4 * lg;
#pragma unroll
  for (int dt = 0; dt < 4; ++dt) {
    ushort4 o;
    o.x = f2bf(oacc[dt][0] * inv);
    o.y = f2bf(oacc[dt][1] * inv);
    o.z = f2bf(oacc[dt][2] * inv);
    o.w = f2bf(oacc[dt][3] * inv);
    *(ushort4*)(Ob + obase + 16 * dt) = o;
  }
}

extern "C" void kernel_launch(void* const* d_in, const int* in_sizes, int n_in,
                              void* d_out, int out_size, void* d_ws, size_t ws_size,
                              hipStream_t stream) {
  const float* x      = (const float*)d_in[0];
  const float* pos    = (const float*)d_in[1];
  const float* qkv_w  = (const float*)d_in[2];
  const float* proj_w = (const float*)d_in[3];
  const float* proj_b = (const float*)d_in[4];
  const float* qn_w   = (const float*)d_in[5];
  const float* kn_w   = (const float*)d_in[6];
  char* ws = (char*)d_ws;
  u16*    xb    = (u16*)(ws + 0);          // 6291456
  u16*    wqkv  = (u16*)(ws + 6291456);    // 3538944
  u16*    wproj = (u16*)(ws + 9830400);    // 1179648
  float2* tab   = (float2*)(ws + 11010048);// 1048576
  u16*    Qb    = (u16*)(ws + 12058624);   // 6291456
  u16*    Kb    = (u16*)(ws + 18350080);   // 6291456
  u16*    Vtb   = (u16*)(ws + 24641536);   // 6291456
  u16*    Ob    = (u16*)(ws + 30932992);   // 6291456 -> total 37224448
  float* out = (float*)d_out;

  const int na4 = TOK * DIM / 4, nb4 = QKVN * DIM / 4, nc4 = DIM * DIM / 4;
  const int ntot = na4 + nb4 + nc4 + TOK * 32;
  conv_all<<<(ntot + 255) / 256, 256, 0, stream>>>(
      x, xb, na4, qkv_w, wqkv, nb4, proj_w, wproj, nc4, pos, tab);

  dim3 g1(TOK / 128, QKVN / 128);
  gemm_qkv<<<g1, 512, 0, stream>>>(xb, wqkv, qn_w, kn_w, tab, Qb, Kb, Vtb);

  attn<<<SEQ / 64 * BATCH * NH, 512, 0, stream>>>(Qb, Kb, Vtb, Ob);

  dim3 g3(TOK / 64, DIM / 64);
  gemm64<<<g3, 256, 0, stream>>>(Ob, wproj, out, proj_b, TOK, DIM, DIM);
}

// Round 9
// 91.692 us; speedup vs baseline: 1.2613x; 1.0279x over previous
//
#include <hip/hip_runtime.h>
#include <hip/hip_bf16.h>
#include <math.h>

#define DIM 768
#define NH 12
#define DH 64
#define SEQ 2048
#define BATCH 2
#define TOK (BATCH*SEQ)   // 4096
#define QKVN (3*DIM)      // 2304

typedef __attribute__((ext_vector_type(8))) short bf16x8;
typedef __attribute__((ext_vector_type(4))) float f32x4;
typedef __attribute__((ext_vector_type(2))) unsigned int u32x2;
typedef unsigned short u16;

#define VM0 asm volatile("s_waitcnt vmcnt(0)" ::: "memory")
#define VM2 asm volatile("s_waitcnt vmcnt(2)" ::: "memory")
#define VM4 asm volatile("s_waitcnt vmcnt(4)" ::: "memory")
#define VM8 asm volatile("s_waitcnt vmcnt(8)" ::: "memory")
#define LGKM0 asm volatile("s_waitcnt lgkmcnt(0)" ::: "memory")
#define BAR() __builtin_amdgcn_s_barrier()

__device__ inline u16 f2bf(float f) {
  union { float f; unsigned u; } v; v.f = f;
  unsigned u = v.u;
  u += 0x7fffu + ((u >> 16) & 1u);   // round-to-nearest-even
  return (u16)(u >> 16);
}

__device__ inline int pkbf(float a, float b) {   // packed bf16 pair (RNE)
  __hip_bfloat162 h = __float22bfloat162_rn(make_float2(a, b));
  int r; __builtin_memcpy(&r, &h, 4); return r;
}

// One launch: convert x, qkv_w, proj_w to bf16 AND build the rope cos/sin table.
__global__ void conv_all(const float* __restrict__ a, u16* __restrict__ ao, int na4,
                         const float* __restrict__ b, u16* __restrict__ bo, int nb4,
                         const float* __restrict__ c, u16* __restrict__ co, int nc4,
                         const float* __restrict__ pos, float2* __restrict__ tab) {
  int i4 = blockIdx.x * blockDim.x + threadIdx.x;
  const int nconv = na4 + nb4 + nc4;
  if (i4 < nconv) {
    const float* src; u16* dst; int off;
    if (i4 < na4)            { src = a; dst = ao; off = i4; }
    else if (i4 < na4 + nb4) { src = b; dst = bo; off = i4 - na4; }
    else                     { src = c; dst = co; off = i4 - na4 - nb4; }
    float4 v = ((const float4*)src)[off];
    ushort4 o;
    o.x = f2bf(v.x); o.y = f2bf(v.y); o.z = f2bf(v.z); o.w = f2bf(v.w);
    ((ushort4*)dst)[off] = o;
    return;
  }
  int e = i4 - nconv;                 // rope table: 4096*32 entries
  if (e >= TOK * 32) return;
  int t = e >> 5, p = e & 31;
  float cs = 1.f, sn = 0.f;
  if (p < 30) {
    int axis = p / 10, fi = p % 10;
    float freq = exp2f(-(float)fi * 1.3287712379549449f); // log2(10000)/10
    float ang = pos[t * 3 + axis] * freq;
    cs = cosf(ang); sn = sinf(ang);
  }
  tab[e] = make_float2(cs, sn);
}

#define GLL(g, s) __builtin_amdgcn_global_load_lds((const __attribute__((address_space(1))) void*)(g), (__attribute__((address_space(3))) void*)(s), 16, 0, 0)

// Proj GEMM: C = A * W^T + bias, bf16 in, fp32 out. 64x64 tile, 4 waves of
// 32x32 -> grid 64x12=768 blocks (3/CU, 12 waves/CU).
__global__ __launch_bounds__(256, 6) void gemm64(
    const u16* __restrict__ A, const u16* __restrict__ W,
    float* __restrict__ C, const float* __restrict__ bias,
    int M, int Nn, int K)
{
  __shared__ u16 As[2][64 * 32];
  __shared__ u16 Bs[2][64 * 32];
  const int t = threadIdx.x;
  const int w = t >> 6, l = t & 63;
  const int lr = l & 15, lg = l >> 4;
  const int wr = w >> 1, wc = w & 1;
  const int m0 = blockIdx.x * 64;
  const int n0 = blockIdx.y * 64;
  f32x4 acc[2][2] = {};
  const int srow = t >> 2;
  const int scol = (t & 3) * 8;
  const u16* aSrc = A + (size_t)(m0 + srow) * K + scol;
  const u16* bSrc = W + (size_t)(n0 + srow) * K + scol;
  const int NT = K / 32;

  GLL(aSrc, &As[0][w * 512]);
  GLL(bSrc, &Bs[0][w * 512]);

  for (int kt = 0; kt < NT; ++kt) {
    const int cur = kt & 1;
    if (kt + 1 < NT) {
      GLL(aSrc + (kt + 1) * 32, &As[cur ^ 1][w * 512]);
      GLL(bSrc + (kt + 1) * 32, &Bs[cur ^ 1][w * 512]);
      VM2;
    } else {
      VM0;
    }
    BAR();
    bf16x8 af[2], bff[2];
#pragma unroll
    for (int mi = 0; mi < 2; ++mi)
      af[mi] = *(const bf16x8*)(&As[cur][0] + (wr * 32 + mi * 16 + lr) * 32 + lg * 8);
#pragma unroll
    for (int ni = 0; ni < 2; ++ni)
      bff[ni] = *(const bf16x8*)(&Bs[cur][0] + (wc * 32 + ni * 16 + lr) * 32 + lg * 8);
#pragma unroll
    for (int mi = 0; mi < 2; ++mi)
#pragma unroll
      for (int ni = 0; ni < 2; ++ni)
        acc[mi][ni] = __builtin_amdgcn_mfma_f32_16x16x32_bf16(af[mi], bff[ni], acc[mi][ni], 0, 0, 0);
    LGKM0;
    BAR();
  }

#pragma unroll
  for (int mi = 0; mi < 2; ++mi)
#pragma unroll
    for (int ni = 0; ni < 2; ++ni)
#pragma unroll
      for (int r = 0; r < 4; ++r) {
        int row = m0 + wr * 32 + mi * 16 + lg * 4 + r;
        int col = n0 + wc * 32 + ni * 16 + lr;
        C[(size_t)row * Nn + col] = acc[mi][ni][r] + bias[col];
      }
}

// QKV GEMM with fused RMSNorm + RoPE + layout epilogue. 512 thr / 8 waves.
__global__ __launch_bounds__(512, 4) void gemm_qkv(
    const u16* __restrict__ A, const u16* __restrict__ W,
    const float* __restrict__ qn_w, const float* __restrict__ kn_w,
    const float2* __restrict__ tab,
    u16* __restrict__ Qb, u16* __restrict__ Kb, u16* __restrict__ Vtb)
{
  __shared__ u16 As[2][128 * 32];
  __shared__ u16 Bs[2][128 * 32];
  const int K = DIM;
  const int t = threadIdx.x;
  const int w = t >> 6, l = t & 63;
  const int lr = l & 15, lg = l >> 4;
  const int wr = w >> 1, wc = w & 1;      // 4 x 2 waves
  const int m0 = blockIdx.x * 128;
  const int n0 = blockIdx.y * 128;
  f32x4 acc[2][4] = {};
  const int srow = t >> 2;                // 0..127
  const int scol = (t & 3) * 8;
  const u16* aSrc = A + (size_t)(m0 + srow) * K + scol;
  const u16* bSrc = W + (size_t)(n0 + srow) * K + scol;
  const int NT = K / 32;

  GLL(aSrc, &As[0][w * 512]);
  GLL(bSrc, &Bs[0][w * 512]);

  for (int kt = 0; kt < NT; ++kt) {
    const int cur = kt & 1;
    if (kt + 1 < NT) {
      GLL(aSrc + (kt + 1) * 32, &As[cur ^ 1][w * 512]);
      GLL(bSrc + (kt + 1) * 32, &Bs[cur ^ 1][w * 512]);
      VM2;
    } else {
      VM0;
    }
    BAR();
    bf16x8 af[2], bff[4];
#pragma unroll
    for (int mi = 0; mi < 2; ++mi)
      af[mi] = *(const bf16x8*)(&As[cur][0] + (wr * 32 + mi * 16 + lr) * 32 + lg * 8);
#pragma unroll
    for (int ni = 0; ni < 4; ++ni)
      bff[ni] = *(const bf16x8*)(&Bs[cur][0] + (wc * 64 + ni * 16 + lr) * 32 + lg * 8);
#pragma unroll
    for (int mi = 0; mi < 2; ++mi)
#pragma unroll
      for (int ni = 0; ni < 4; ++ni)
        acc[mi][ni] = __builtin_amdgcn_mfma_f32_16x16x32_bf16(af[mi], bff[ni], acc[mi][ni], 0, 0, 0);
    LGKM0;
    BAR();
  }

  // ---- fused epilogue ----
  const int chunk = (n0 >> 6) + wc;        // 0..35 over [3 types][12 heads]
  const int tt = chunk / 12;               // 0=q 1=k 2=v
  const int h  = chunk % 12;
  const int bB = m0 >> 11;                 // batch (block-const)
  const int bh = bB * NH + h;

  if (tt == 2) {
#pragma unroll
    for (int mi = 0; mi < 2; ++mi) {
      const int nbase = (m0 + wr * 32 + mi * 16 + lg * 4) & 2047;
#pragma unroll
      for (int ni = 0; ni < 4; ++ni) {
        const int d = ni * 16 + lr;
        ushort4 o;
        o.x = f2bf(acc[mi][ni][0]); o.y = f2bf(acc[mi][ni][1]);
        o.z = f2bf(acc[mi][ni][2]); o.w = f2bf(acc[mi][ni][3]);
        *(ushort4*)(Vtb + ((size_t)bh * DH + d) * SEQ + nbase) = o;
      }
    }
  } else {
    const float* wv = (tt == 0 ? qn_w : kn_w);
    const float qs = (tt == 0 ? 0.125f * 1.4426950408889634f : 1.f);
    float wgt[4];
#pragma unroll
    for (int ni = 0; ni < 4; ++ni) wgt[ni] = wv[ni * 16 + lr];
    u16* outp = (tt == 0 ? Qb : Kb) + (size_t)bh * SEQ * DH;
#pragma unroll
    for (int mi = 0; mi < 2; ++mi) {
#pragma unroll
      for (int r = 0; r < 4; ++r) {
        float ss = 0.f;
#pragma unroll
        for (int ni = 0; ni < 4; ++ni) ss += acc[mi][ni][r] * acc[mi][ni][r];
        ss += __shfl_xor(ss, 1, 64);
        ss += __shfl_xor(ss, 2, 64);
        ss += __shfl_xor(ss, 4, 64);
        ss += __shfl_xor(ss, 8, 64);
        const float rms = rsqrtf(ss * (1.f / 64.f) + 1e-6f);
        const int trow = m0 + wr * 32 + mi * 16 + lg * 4 + r;
        const float2* tl = tab + trow * 32;
        u16* rowp = outp + (size_t)(trow & 2047) * DH;
#pragma unroll
        for (int ni = 0; ni < 4; ++ni) {
          const int d = ni * 16 + lr;
          float v = acc[mi][ni][r] * rms * wgt[ni];
          float vp = __shfl_xor(v, 1, 64);
          float2 cssn = tl[ni * 8 + (lr >> 1)];
          float sgn = (d & 1) ? cssn.y : -cssn.y;
          rowp[d] = f2bf((v * cssn.x + vp * sgn) * qs);
        }
      }
    }
  }
}

// Flash attention v3: 4 waves = (qg in {0,1}) x (half in {0,1}); each wave
// 32 q-rows (two 16-q sets A/B) x 64 KV (its half). Halved LDS traffic per
// q*kv area (each ds_read feeds 2 MFMA); lsum via mfma(ones,P) column-sum
// (kills 32 VALU adds/iter + end shuffles). Static-shift softmax (exact).
// K pair-dbuf (32KB) + V pair buffer (16KB). T4 counted vmcnt (4-GLL groups).
__global__ __launch_bounds__(256, 3) void attn(
    const u16* __restrict__ Qb, const u16* __restrict__ Kb,
    const u16* __restrict__ Vtb, u16* __restrict__ Ob)
{
  __shared__ u16 Ks[2][2][64 * 64];   // [pair dbuf][tile-in-pair]
  __shared__ u16 Vs[2][64 * 64];      // [tile-in-pair]
  const int tid = threadIdx.x;
  const int w = tid >> 6, l = tid & 63;
  const int lr = l & 15, lg = l >> 4;
  const int qg = w & 1, half = w >> 1;
  const int wg = blockIdx.x;
  const int swz = (wg & 7) * 96 + (wg >> 3);   // bijective, 768 % 8 == 0
  const int bh = swz >> 5;
  const int q0 = (swz & 31) * 64;
  const u16* Qp = Qb + (size_t)bh * SEQ * DH;
  const u16* Kp = Kb + (size_t)bh * SEQ * DH;
  const u16* Vp = Vtb + (size_t)bh * DH * SEQ;

  // Q B-frags for two 16-row sets
  const int qrA = q0 + qg * 32 + lr;
  const bf16x8 bq0a = *(const bf16x8*)(Qp + (size_t)qrA * DH + 8 * lg);
  const bf16x8 bq1a = *(const bf16x8*)(Qp + (size_t)qrA * DH + 32 + 8 * lg);
  const bf16x8 bq0b = *(const bf16x8*)(Qp + (size_t)(qrA + 16) * DH + 8 * lg);
  const bf16x8 bq1b = *(const bf16x8*)(Qp + (size_t)(qrA + 16) * DH + 32 + 8 * lg);

  // staging: 256 threads, 2 GLL rounds per 8KB tile (rows 0-31, 32-63)
  const int srow = tid >> 3;                  // 0..31
  const int sc16 = (tid & 7) ^ (srow & 7);
  const u16* kSrc = Kp + (size_t)srow * DH + sc16 * 8;    // + kt*4096
  const u16* vSrc = Vp + (size_t)srow * SEQ + sc16 * 8;   // + kt*64

  const int frow = (lr & 3) | ((lr & 4) << 1) | ((lr & 8) >> 1);
  const int ksw = frow & 7;
  const int vsw = lr & 7;

  bf16x8 vone;
#pragma unroll
  for (int j = 0; j < 8; ++j) vone[j] = (short)0x3F80;

  f32x4 oaccA[4] = {}, oaccB[4] = {};
  f32x4 laccA = {}, laccB = {};

  // prologue: stage pair 0 (K tiles 0,1 ; V tiles 0,1), 8 GLLs
  GLL(kSrc,          &Ks[0][0][w * 512]);
  GLL(kSrc + 2048,   &Ks[0][0][w * 512 + 2048]);
  GLL(kSrc + 4096,   &Ks[0][1][w * 512]);
  GLL(kSrc + 6144,   &Ks[0][1][w * 512 + 2048]);
  GLL(vSrc,          &Vs[0][w * 512]);
  GLL(vSrc + 65536,  &Vs[0][w * 512 + 2048]);
  GLL(vSrc + 64,     &Vs[1][w * 512]);
  GLL(vSrc + 64 + 65536, &Vs[1][w * 512 + 2048]);

  for (int i = 0; i < 16; ++i) {
    const int p = i & 1;
    if (i + 1 < 16) {   // K prefetch for pair i+1 (4 GLL)
      const size_t ko = (size_t)(2 * i + 2) * 4096;
      GLL(kSrc + ko,        &Ks[p ^ 1][0][w * 512]);
      GLL(kSrc + ko + 2048, &Ks[p ^ 1][0][w * 512 + 2048]);
      GLL(kSrc + ko + 4096, &Ks[p ^ 1][1][w * 512]);
      GLL(kSrc + ko + 6144, &Ks[p ^ 1][1][w * 512 + 2048]);
      VM8;   // K(i) landed; V(i)+K(i+1) in flight
    } else {
      VM4;   // K(15) landed; V(15) in flight
    }
    BAR();
    const u16* Kt = &Ks[p][half][0];
    const u16* Vt = &Vs[half][0];

    // QK for both q-sets: each K read feeds 2 MFMA
    f32x4 paccA[4] = {}, paccB[4] = {};
    __builtin_amdgcn_s_setprio(1);
#pragma unroll
    for (int c = 0; c < 4; ++c) {
      const int rbase = (16 * c + frow) * 64;
      bf16x8 ka = *(const bf16x8*)(Kt + rbase + ((lg ^ ksw) * 8));
      bf16x8 kb = *(const bf16x8*)(Kt + rbase + (((4 + lg) ^ ksw) * 8));
      paccA[c] = __builtin_amdgcn_mfma_f32_16x16x32_bf16(ka, bq0a, paccA[c], 0, 0, 0);
      paccA[c] = __builtin_amdgcn_mfma_f32_16x16x32_bf16(kb, bq1a, paccA[c], 0, 0, 0);
      paccB[c] = __builtin_amdgcn_mfma_f32_16x16x32_bf16(ka, bq0b, paccB[c], 0, 0, 0);
      paccB[c] = __builtin_amdgcn_mfma_f32_16x16x32_bf16(kb, bq1b, paccB[c], 0, 0, 0);
    }
    __builtin_amdgcn_s_setprio(0);

    if (i + 1 < 16) { VM4; } else { VM0; }   // V(i) landed
    LGKM0;
    BAR();   // alpha: V readable; K reads of this iter complete

    // per-g: exp -> pack -> PV (keeps pp liveness at 16 floats/set)
#pragma unroll
    for (int g = 0; g < 2; ++g) {
      const int clo = 2 * g, chi = 2 * g + 1;
      float pA[8], pB[8];
#pragma unroll
      for (int r = 0; r < 4; ++r) {
        pA[r]     = __builtin_amdgcn_exp2f(paccA[clo][r] - 12.f);
        pA[4 + r] = __builtin_amdgcn_exp2f(paccA[chi][r] - 12.f);
        pB[r]     = __builtin_amdgcn_exp2f(paccB[clo][r] - 12.f);
        pB[4 + r] = __builtin_amdgcn_exp2f(paccB[chi][r] - 12.f);
      }
      u32x2 a0 = __builtin_amdgcn_permlane32_swap((unsigned)pkbf(pA[0], pA[1]),
                                                  (unsigned)pkbf(pA[4], pA[5]), false, false);
      u32x2 a1 = __builtin_amdgcn_permlane32_swap((unsigned)pkbf(pA[2], pA[3]),
                                                  (unsigned)pkbf(pA[6], pA[7]), false, false);
      u32x2 b0 = __builtin_amdgcn_permlane32_swap((unsigned)pkbf(pB[0], pB[1]),
                                                  (unsigned)pkbf(pB[4], pB[5]), false, false);
      u32x2 b1 = __builtin_amdgcn_permlane32_swap((unsigned)pkbf(pB[2], pB[3]),
                                                  (unsigned)pkbf(pB[6], pB[7]), false, false);
      union { unsigned d[4]; bf16x8 v; } puA, puB;
      puA.d[0] = a0[0]; puA.d[1] = a1[0]; puA.d[2] = a0[1]; puA.d[3] = a1[1];
      puB.d[0] = b0[0]; puB.d[1] = b1[0]; puB.d[2] = b0[1]; puB.d[3] = b1[1];
      __builtin_amdgcn_s_setprio(1);
#pragma unroll
      for (int dt = 0; dt < 4; ++dt) {
        bf16x8 va = *(const bf16x8*)(Vt + (16 * dt + lr) * 64 + (((4 * g + lg) ^ vsw) * 8));
        oaccA[dt] = __builtin_amdgcn_mfma_f32_16x16x32_bf16(va, puA.v, oaccA[dt], 0, 0, 0);
        oaccB[dt] = __builtin_amdgcn_mfma_f32_16x16x32_bf16(va, puB.v, oaccB[dt], 0, 0, 0);
      }
      laccA = __builtin_amdgcn_mfma_f32_16x16x32_bf16(vone, puA.v, laccA, 0, 0, 0);
      laccB = __builtin_amdgcn_mfma_f32_16x16x32_bf16(vone, puB.v, laccB, 0, 0, 0);
      __builtin_amdgcn_s_setprio(0);
    }

    LGKM0;
    BAR();   // beta: all waves done reading Vs

    if (i + 1 < 16) {   // V stage for pair i+1 (4 GLL; lands during next QK)
      const size_t vo = (size_t)(2 * i + 2) * 64;
      GLL(vSrc + vo,              &Vs[0][w * 512]);
      GLL(vSrc + vo + 65536,      &Vs[0][w * 512 + 2048]);
      GLL(vSrc + vo + 64,         &Vs[1][w * 512]);
      GLL(vSrc + vo + 64 + 65536, &Vs[1][w * 512 + 2048]);
    }
  }

  // combine halves (static shift => additive partials). lsum = lacc[0]
  // (mfma ones-column-sum: all rows equal, col = q = lr).
  float* scr = (float*)&Ks[0][0][0];
  const int sidA = (qg * 2 + 0) * 64 + l;
  const int sidB = (qg * 2 + 1) * 64 + l;
  if (half == 1) {
#pragma unroll
    for (int dt = 0; dt < 4; ++dt)
#pragma unroll
      for (int r = 0; r < 4; ++r) {
        scr[sidA * 17 + dt * 4 + r] = oaccA[dt][r];
        scr[sidB * 17 + dt * 4 + r] = oaccB[dt][r];
      }
    scr[sidA * 17 + 16] = laccA[0];
    scr[sidB * 17 + 16] = laccB[0];
  }
  __syncthreads();
  if (half == 1) return;
#pragma unroll
  for (int dt = 0; dt < 4; ++dt)
#pragma unroll
    for (int r = 0; r < 4; ++r) {
      oaccA[dt][r] += scr[sidA * 17 + dt * 4 + r];
      oaccB[dt][r] += scr[sidB * 17 + dt * 4 + r];
    }
  const float invA = 1.f / (laccA[0] + scr[sidA * 17 + 16]);
  const float invB = 1.f / (laccB[0] + scr[sidB * 17 + 16]);

  const int b = bh / NH, h = bh % NH;
  const int qA = q0 + qg * 32 + lr;
  size_t obA = (size_t)(b * SEQ + qA) * DIM + h * DH + 4 * lg;
  size_t obB = (size_t)(b * SEQ + qA + 16) * DIM + h * DH + 4 * lg;
#pragma unroll
  for (int dt = 0; dt < 4; ++dt) {
    ushort4 oA, oB;
    oA.x = f2bf(oaccA[dt][0] * invA); oA.y = f2bf(oaccA[dt][1] * invA);
    oA.z = f2bf(oaccA[dt][2] * invA); oA.w = f2bf(oaccA[dt][3] * invA);
    oB.x = f2bf(oaccB[dt][0] * invB); oB.y = f2bf(oaccB[dt][1] * invB);
    oB.z = f2bf(oaccB[dt][2] * invB); oB.w = f2bf(oaccB[dt][3] * invB);
    *(ushort4*)(Ob + obA + 16 * dt) = oA;
    *(ushort4*)(Ob + obB + 16 * dt) = oB;
  }
}

extern "C" void kernel_launch(void* const* d_in, const int* in_sizes, int n_in,
                              void* d_out, int out_size, void* d_ws, size_t ws_size,
                              hipStream_t stream) {
  const float* x      = (const float*)d_in[0];
  const float* pos    = (const float*)d_in[1];
  const float* qkv_w  = (const float*)d_in[2];
  const float* proj_w = (const float*)d_in[3];
  const float* proj_b = (const float*)d_in[4];
  const float* qn_w   = (const float*)d_in[5];
  const float* kn_w   = (const float*)d_in[6];
  char* ws = (char*)d_ws;
  u16*    xb    = (u16*)(ws + 0);          // 6291456
  u16*    wqkv  = (u16*)(ws + 6291456);    // 3538944
  u16*    wproj = (u16*)(ws + 9830400);    // 1179648
  float2* tab   = (float2*)(ws + 11010048);// 1048576
  u16*    Qb    = (u16*)(ws + 12058624);   // 6291456
  u16*    Kb    = (u16*)(ws + 18350080);   // 6291456
  u16*    Vtb   = (u16*)(ws + 24641536);   // 6291456
  u16*    Ob    = (u16*)(ws + 30932992);   // 6291456 -> total 37224448
  float* out = (float*)d_out;

  const int na4 = TOK * DIM / 4, nb4 = QKVN * DIM / 4, nc4 = DIM * DIM / 4;
  const int ntot = na4 + nb4 + nc4 + TOK * 32;
  conv_all<<<(ntot + 255) / 256, 256, 0, stream>>>(
      x, xb, na4, qkv_w, wqkv, nb4, proj_w, wproj, nc4, pos, tab);

  dim3 g1(TOK / 128, QKVN / 128);
  gemm_qkv<<<g1, 512, 0, stream>>>(xb, wqkv, qn_w, kn_w, tab, Qb, Kb, Vtb);

  attn<<<SEQ / 64 * BATCH * NH, 256, 0, stream>>>(Qb, Kb, Vtb, Ob);

  dim3 g3(TOK / 64, DIM / 64);
  gemm64<<<g3, 256, 0, stream>>>(Ob, wproj, out, proj_b, TOK, DIM, DIM);
}

// Round 10
// 89.886 us; speedup vs baseline: 1.2867x; 1.0201x over previous
//
#include <hip/hip_runtime.h>
#include <hip/hip_bf16.h>
#include <math.h>

#define DIM 768
#define NH 12
#define DH 64
#define SEQ 2048
#define BATCH 2
#define TOK (BATCH*SEQ)   // 4096
#define QKVN (3*DIM)      // 2304

typedef __attribute__((ext_vector_type(8))) short bf16x8;
typedef __attribute__((ext_vector_type(4))) float f32x4;
typedef __attribute__((ext_vector_type(2))) unsigned int u32x2;
typedef unsigned short u16;

#define VM0 asm volatile("s_waitcnt vmcnt(0)" ::: "memory")
#define VM4 asm volatile("s_waitcnt vmcnt(4)" ::: "memory")
#define LGKM0 asm volatile("s_waitcnt lgkmcnt(0)" ::: "memory")
#define BAR() __builtin_amdgcn_s_barrier()

__device__ inline u16 f2bf(float f) {
  union { float f; unsigned u; } v; v.f = f;
  unsigned u = v.u;
  u += 0x7fffu + ((u >> 16) & 1u);   // round-to-nearest-even
  return (u16)(u >> 16);
}

__device__ inline int pkbf(float a, float b) {   // packed bf16 pair (RNE)
  __hip_bfloat162 h = __float22bfloat162_rn(make_float2(a, b));
  int r; __builtin_memcpy(&r, &h, 4); return r;
}

// One launch: convert x, qkv_w, proj_w to bf16 AND build the rope cos/sin table.
__global__ void conv_all(const float* __restrict__ a, u16* __restrict__ ao, int na4,
                         const float* __restrict__ b, u16* __restrict__ bo, int nb4,
                         const float* __restrict__ c, u16* __restrict__ co, int nc4,
                         const float* __restrict__ pos, float2* __restrict__ tab) {
  int i4 = blockIdx.x * blockDim.x + threadIdx.x;
  const int nconv = na4 + nb4 + nc4;
  if (i4 < nconv) {
    const float* src; u16* dst; int off;
    if (i4 < na4)            { src = a; dst = ao; off = i4; }
    else if (i4 < na4 + nb4) { src = b; dst = bo; off = i4 - na4; }
    else                     { src = c; dst = co; off = i4 - na4 - nb4; }
    float4 v = ((const float4*)src)[off];
    ushort4 o;
    o.x = f2bf(v.x); o.y = f2bf(v.y); o.z = f2bf(v.z); o.w = f2bf(v.w);
    ((ushort4*)dst)[off] = o;
    return;
  }
  int e = i4 - nconv;                 // rope table: 4096*32 entries
  if (e >= TOK * 32) return;
  int t = e >> 5, p = e & 31;
  float cs = 1.f, sn = 0.f;
  if (p < 30) {
    int axis = p / 10, fi = p % 10;
    float freq = exp2f(-(float)fi * 1.3287712379549449f); // log2(10000)/10
    float ang = pos[t * 3 + axis] * freq;
    cs = cosf(ang); sn = sinf(ang);
  }
  tab[e] = make_float2(cs, sn);
}

#define GLL(g, s) __builtin_amdgcn_global_load_lds((const __attribute__((address_space(1))) void*)(g), (__attribute__((address_space(3))) void*)(s), 16, 0, 0)

// Proj GEMM: C = A * W^T + bias. 64x64 tile, BK=64 (NT=6, 12 barriers),
// XOR-swizzled LDS (128B row stride needs it). 32KB LDS -> 5 blocks/CU.
__global__ __launch_bounds__(256, 4) void gemm64(
    const u16* __restrict__ A, const u16* __restrict__ W,
    float* __restrict__ C, const float* __restrict__ bias,
    int M, int Nn, int K)
{
  __shared__ u16 As[2][64 * 64];
  __shared__ u16 Bs[2][64 * 64];
  const int t = threadIdx.x;
  const int w = t >> 6, l = t & 63;
  const int lr = l & 15, lg = l >> 4;
  const int wr = w >> 1, wc = w & 1;
  const int m0 = blockIdx.x * 64;
  const int n0 = blockIdx.y * 64;
  f32x4 acc[2][2] = {};
  const int srow = t >> 3;                      // 0..31
  const int scol = (((t & 7) ^ (srow & 7)) * 8);// pre-swizzled source chunk
  const u16* aSrc = A + (size_t)(m0 + srow) * K + scol;
  const u16* bSrc = W + (size_t)(n0 + srow) * K + scol;
  const size_t r32 = (size_t)32 * K;
  const int sw = lr & 7;
  const int NT = K / 64;

  GLL(aSrc,       &As[0][w * 512]);
  GLL(aSrc + r32, &As[0][2048 + w * 512]);
  GLL(bSrc,       &Bs[0][w * 512]);
  GLL(bSrc + r32, &Bs[0][2048 + w * 512]);

  for (int kt = 0; kt < NT; ++kt) {
    const int cur = kt & 1;
    if (kt + 1 < NT) {
      const int k0 = (kt + 1) * 64;
      GLL(aSrc + k0,       &As[cur ^ 1][w * 512]);
      GLL(aSrc + r32 + k0, &As[cur ^ 1][2048 + w * 512]);
      GLL(bSrc + k0,       &Bs[cur ^ 1][w * 512]);
      GLL(bSrc + r32 + k0, &Bs[cur ^ 1][2048 + w * 512]);
      VM4;
    } else {
      VM0;
    }
    BAR();
#pragma unroll
    for (int kk = 0; kk < 2; ++kk) {
      bf16x8 af[2], bff[2];
#pragma unroll
      for (int mi = 0; mi < 2; ++mi)
        af[mi] = *(const bf16x8*)(&As[cur][0] + (wr * 32 + mi * 16 + lr) * 64 + (((kk * 4 + lg) ^ sw) * 8));
#pragma unroll
      for (int ni = 0; ni < 2; ++ni)
        bff[ni] = *(const bf16x8*)(&Bs[cur][0] + (wc * 32 + ni * 16 + lr) * 64 + (((kk * 4 + lg) ^ sw) * 8));
#pragma unroll
      for (int mi = 0; mi < 2; ++mi)
#pragma unroll
        for (int ni = 0; ni < 2; ++ni)
          acc[mi][ni] = __builtin_amdgcn_mfma_f32_16x16x32_bf16(af[mi], bff[ni], acc[mi][ni], 0, 0, 0);
    }
    LGKM0;
    BAR();
  }

#pragma unroll
  for (int mi = 0; mi < 2; ++mi)
#pragma unroll
    for (int ni = 0; ni < 2; ++ni)
#pragma unroll
      for (int r = 0; r < 4; ++r) {
        int row = m0 + wr * 32 + mi * 16 + lg * 4 + r;
        int col = n0 + wc * 32 + ni * 16 + lr;
        C[(size_t)row * Nn + col] = acc[mi][ni][r] + bias[col];
      }
}

// QKV GEMM + fused RMSNorm/RoPE/layout. 512 thr / 8 waves, BK=64 (NT=12,
// 24 barriers), XOR-swizzled LDS. 64KB LDS -> 2 blocks/CU (= grid's 2.25).
__global__ __launch_bounds__(512, 2) void gemm_qkv(
    const u16* __restrict__ A, const u16* __restrict__ W,
    const float* __restrict__ qn_w, const float* __restrict__ kn_w,
    const float2* __restrict__ tab,
    u16* __restrict__ Qb, u16* __restrict__ Kb, u16* __restrict__ Vtb)
{
  __shared__ u16 As[2][128 * 64];
  __shared__ u16 Bs[2][128 * 64];
  const int K = DIM;
  const int t = threadIdx.x;
  const int w = t >> 6, l = t & 63;
  const int lr = l & 15, lg = l >> 4;
  const int wr = w >> 1, wc = w & 1;      // 4 x 2 waves, 32x64 each
  const int m0 = blockIdx.x * 128;
  const int n0 = blockIdx.y * 128;
  f32x4 acc[2][4] = {};
  const int srow = t >> 3;                      // 0..63
  const int scol = (((t & 7) ^ (srow & 7)) * 8);
  const u16* aSrc = A + (size_t)(m0 + srow) * K + scol;
  const u16* bSrc = W + (size_t)(n0 + srow) * K + scol;
  const size_t r64 = (size_t)64 * K;
  const int sw = lr & 7;
  const int NT = K / 64;

  GLL(aSrc,       &As[0][w * 512]);
  GLL(aSrc + r64, &As[0][4096 + w * 512]);
  GLL(bSrc,       &Bs[0][w * 512]);
  GLL(bSrc + r64, &Bs[0][4096 + w * 512]);

  for (int kt = 0; kt < NT; ++kt) {
    const int cur = kt & 1;
    if (kt + 1 < NT) {
      const int k0 = (kt + 1) * 64;
      GLL(aSrc + k0,       &As[cur ^ 1][w * 512]);
      GLL(aSrc + r64 + k0, &As[cur ^ 1][4096 + w * 512]);
      GLL(bSrc + k0,       &Bs[cur ^ 1][w * 512]);
      GLL(bSrc + r64 + k0, &Bs[cur ^ 1][4096 + w * 512]);
      VM4;
    } else {
      VM0;
    }
    BAR();
#pragma unroll
    for (int kk = 0; kk < 2; ++kk) {
      bf16x8 af[2], bff[4];
#pragma unroll
      for (int mi = 0; mi < 2; ++mi)
        af[mi] = *(const bf16x8*)(&As[cur][0] + (wr * 32 + mi * 16 + lr) * 64 + (((kk * 4 + lg) ^ sw) * 8));
#pragma unroll
      for (int ni = 0; ni < 4; ++ni)
        bff[ni] = *(const bf16x8*)(&Bs[cur][0] + (wc * 64 + ni * 16 + lr) * 64 + (((kk * 4 + lg) ^ sw) * 8));
#pragma unroll
      for (int mi = 0; mi < 2; ++mi)
#pragma unroll
        for (int ni = 0; ni < 4; ++ni)
          acc[mi][ni] = __builtin_amdgcn_mfma_f32_16x16x32_bf16(af[mi], bff[ni], acc[mi][ni], 0, 0, 0);
    }
    LGKM0;
    BAR();
  }

  // ---- fused epilogue ----
  const int chunk = (n0 >> 6) + wc;        // 0..35 over [3 types][12 heads]
  const int tt = chunk / 12;               // 0=q 1=k 2=v
  const int h  = chunk % 12;
  const int bB = m0 >> 11;                 // batch (block-const)
  const int bh = bB * NH + h;

  if (tt == 2) {
#pragma unroll
    for (int mi = 0; mi < 2; ++mi) {
      const int nbase = (m0 + wr * 32 + mi * 16 + lg * 4) & 2047;
#pragma unroll
      for (int ni = 0; ni < 4; ++ni) {
        const int d = ni * 16 + lr;
        ushort4 o;
        o.x = f2bf(acc[mi][ni][0]); o.y = f2bf(acc[mi][ni][1]);
        o.z = f2bf(acc[mi][ni][2]); o.w = f2bf(acc[mi][ni][3]);
        *(ushort4*)(Vtb + ((size_t)bh * DH + d) * SEQ + nbase) = o;
      }
    }
  } else {
    const float* wv = (tt == 0 ? qn_w : kn_w);
    const float qs = (tt == 0 ? 0.125f * 1.4426950408889634f : 1.f);
    float wgt[4];
#pragma unroll
    for (int ni = 0; ni < 4; ++ni) wgt[ni] = wv[ni * 16 + lr];
    u16* outp = (tt == 0 ? Qb : Kb) + (size_t)bh * SEQ * DH;
#pragma unroll
    for (int mi = 0; mi < 2; ++mi) {
#pragma unroll
      for (int r = 0; r < 4; ++r) {
        float ss = 0.f;
#pragma unroll
        for (int ni = 0; ni < 4; ++ni) ss += acc[mi][ni][r] * acc[mi][ni][r];
        ss += __shfl_xor(ss, 1, 64);
        ss += __shfl_xor(ss, 2, 64);
        ss += __shfl_xor(ss, 4, 64);
        ss += __shfl_xor(ss, 8, 64);
        const float rms = rsqrtf(ss * (1.f / 64.f) + 1e-6f);
        const int trow = m0 + wr * 32 + mi * 16 + lg * 4 + r;
        const float2* tl = tab + trow * 32;
        u16* rowp = outp + (size_t)(trow & 2047) * DH;
#pragma unroll
        for (int ni = 0; ni < 4; ++ni) {
          const int d = ni * 16 + lr;
          float v = acc[mi][ni][r] * rms * wgt[ni];
          float vp = __shfl_xor(v, 1, 64);
          float2 cssn = tl[ni * 8 + (lr >> 1)];
          float sgn = (d & 1) ? cssn.y : -cssn.y;
          rowp[d] = f2bf((v * cssn.x + vp * sgn) * qs);
        }
      }
    }
  }
}

// Flash attention v4: same v3 tiling (4 waves = 2qg x 2half, 32q x 64kv each)
// but 2 barriers/iter: alpha = vmcnt(0)+BAR (V(i),K(i+1) visible), beta =
// lgkmcnt(0)+BAR then issue V(i+1),K(i+2) into freed buffers. Softmax fully
// hoisted before alpha so the V-wait overlaps exp2/pack VALU; PV is a pure
// 20-MFMA burst. Static-shift softmax (exact); lsum via mfma(ones,P).
__global__ __launch_bounds__(256, 3) void attn(
    const u16* __restrict__ Qb, const u16* __restrict__ Kb,
    const u16* __restrict__ Vtb, u16* __restrict__ Ob)
{
  __shared__ u16 Ks[2][2][64 * 64];   // [pair dbuf][tile-in-pair]
  __shared__ u16 Vs[2][64 * 64];      // [tile-in-pair]
  const int tid = threadIdx.x;
  const int w = tid >> 6, l = tid & 63;
  const int lr = l & 15, lg = l >> 4;
  const int qg = w & 1, half = w >> 1;
  const int wg = blockIdx.x;
  const int swz = (wg & 7) * 96 + (wg >> 3);   // bijective, 768 % 8 == 0
  const int bh = swz >> 5;
  const int q0 = (swz & 31) * 64;
  const u16* Qp = Qb + (size_t)bh * SEQ * DH;
  const u16* Kp = Kb + (size_t)bh * SEQ * DH;
  const u16* Vp = Vtb + (size_t)bh * DH * SEQ;

  const int qrA = q0 + qg * 32 + lr;
  const bf16x8 bq0a = *(const bf16x8*)(Qp + (size_t)qrA * DH + 8 * lg);
  const bf16x8 bq1a = *(const bf16x8*)(Qp + (size_t)qrA * DH + 32 + 8 * lg);
  const bf16x8 bq0b = *(const bf16x8*)(Qp + (size_t)(qrA + 16) * DH + 8 * lg);
  const bf16x8 bq1b = *(const bf16x8*)(Qp + (size_t)(qrA + 16) * DH + 32 + 8 * lg);

  const int srow = tid >> 3;                  // 0..31
  const int sc16 = (tid & 7) ^ (srow & 7);
  const u16* kSrc = Kp + (size_t)srow * DH + sc16 * 8;    // + kt*4096
  const u16* vSrc = Vp + (size_t)srow * SEQ + sc16 * 8;   // + kt*64

  const int frow = (lr & 3) | ((lr & 4) << 1) | ((lr & 8) >> 1);
  const int ksw = frow & 7;
  const int vsw = lr & 7;

  bf16x8 vone;
#pragma unroll
  for (int j = 0; j < 8; ++j) vone[j] = (short)0x3F80;

  f32x4 oaccA[4] = {}, oaccB[4] = {};
  f32x4 laccA = {}, laccB = {};

  // prologue: K(0); drain; barrier; then V(0), K(1) in flight
  GLL(kSrc,          &Ks[0][0][w * 512]);
  GLL(kSrc + 2048,   &Ks[0][0][w * 512 + 2048]);
  GLL(kSrc + 4096,   &Ks[0][1][w * 512]);
  GLL(kSrc + 6144,   &Ks[0][1][w * 512 + 2048]);
  VM0;
  BAR();
  GLL(vSrc,              &Vs[0][w * 512]);
  GLL(vSrc + 65536,      &Vs[0][w * 512 + 2048]);
  GLL(vSrc + 64,         &Vs[1][w * 512]);
  GLL(vSrc + 64 + 65536, &Vs[1][w * 512 + 2048]);
  GLL(kSrc + 8192,   &Ks[1][0][w * 512]);
  GLL(kSrc + 10240,  &Ks[1][0][w * 512 + 2048]);
  GLL(kSrc + 12288,  &Ks[1][1][w * 512]);
  GLL(kSrc + 14336,  &Ks[1][1][w * 512 + 2048]);

  for (int i = 0; i < 16; ++i) {
    const int p = i & 1;
    const u16* Kt = &Ks[p][half][0];
    const u16* Vt = &Vs[half][0];

    // QK: 16 MFMA (K visible since previous alpha/prologue barrier)
    f32x4 paccA[4] = {}, paccB[4] = {};
    __builtin_amdgcn_s_setprio(1);
#pragma unroll
    for (int c = 0; c < 4; ++c) {
      const int rbase = (16 * c + frow) * 64;
      bf16x8 ka = *(const bf16x8*)(Kt + rbase + ((lg ^ ksw) * 8));
      bf16x8 kb = *(const bf16x8*)(Kt + rbase + (((4 + lg) ^ ksw) * 8));
      paccA[c] = __builtin_amdgcn_mfma_f32_16x16x32_bf16(ka, bq0a, paccA[c], 0, 0, 0);
      paccA[c] = __builtin_amdgcn_mfma_f32_16x16x32_bf16(kb, bq1a, paccA[c], 0, 0, 0);
      paccB[c] = __builtin_amdgcn_mfma_f32_16x16x32_bf16(ka, bq0b, paccB[c], 0, 0, 0);
      paccB[c] = __builtin_amdgcn_mfma_f32_16x16x32_bf16(kb, bq1b, paccB[c], 0, 0, 0);
    }
    __builtin_amdgcn_s_setprio(0);

    // softmax fully in-register (overlaps V(i)/K(i+1) landing)
    union { unsigned d[4]; bf16x8 v; } puA[2], puB[2];
#pragma unroll
    for (int g = 0; g < 2; ++g) {
      const int clo = 2 * g, chi = 2 * g + 1;
      float eA[8], eB[8];
#pragma unroll
      for (int r = 0; r < 4; ++r) {
        eA[r]     = __builtin_amdgcn_exp2f(paccA[clo][r] - 12.f);
        eA[4 + r] = __builtin_amdgcn_exp2f(paccA[chi][r] - 12.f);
        eB[r]     = __builtin_amdgcn_exp2f(paccB[clo][r] - 12.f);
        eB[4 + r] = __builtin_amdgcn_exp2f(paccB[chi][r] - 12.f);
      }
      u32x2 a0 = __builtin_amdgcn_permlane32_swap((unsigned)pkbf(eA[0], eA[1]),
                                                  (unsigned)pkbf(eA[4], eA[5]), false, false);
      u32x2 a1 = __builtin_amdgcn_permlane32_swap((unsigned)pkbf(eA[2], eA[3]),
                                                  (unsigned)pkbf(eA[6], eA[7]), false, false);
      u32x2 b0 = __builtin_amdgcn_permlane32_swap((unsigned)pkbf(eB[0], eB[1]),
                                                  (unsigned)pkbf(eB[4], eB[5]), false, false);
      u32x2 b1 = __builtin_amdgcn_permlane32_swap((unsigned)pkbf(eB[2], eB[3]),
                                                  (unsigned)pkbf(eB[6], eB[7]), false, false);
      puA[g].d[0] = a0[0]; puA[g].d[1] = a1[0]; puA[g].d[2] = a0[1]; puA[g].d[3] = a1[1];
      puB[g].d[0] = b0[0]; puB[g].d[1] = b1[0]; puB[g].d[2] = b0[1]; puB[g].d[3] = b1[1];
    }

    VM0;   // V(i) and K(i+1) landed
    BAR(); // alpha: visible to all waves

    // PV: pure MFMA burst
    __builtin_amdgcn_s_setprio(1);
#pragma unroll
    for (int g = 0; g < 2; ++g) {
#pragma unroll
      for (int dt = 0; dt < 4; ++dt) {
        bf16x8 va = *(const bf16x8*)(Vt + (16 * dt + lr) * 64 + (((4 * g + lg) ^ vsw) * 8));
        oaccA[dt] = __builtin_amdgcn_mfma_f32_16x16x32_bf16(va, puA[g].v, oaccA[dt], 0, 0, 0);
        oaccB[dt] = __builtin_amdgcn_mfma_f32_16x16x32_bf16(va, puB[g].v, oaccB[dt], 0, 0, 0);
      }
      laccA = __builtin_amdgcn_mfma_f32_16x16x32_bf16(vone, puA[g].v, laccA, 0, 0, 0);
      laccB = __builtin_amdgcn_mfma_f32_16x16x32_bf16(vone, puB[g].v, laccB, 0, 0, 0);
    }
    __builtin_amdgcn_s_setprio(0);

    LGKM0;  // all my LDS reads of Vs / Ks[p] complete
    BAR();  // beta: buffers free block-wide

    if (i + 1 < 16) {   // V(i+1) -> Vs (flight = next QK+softmax)
      const size_t vo = (size_t)(2 * i + 2) * 64;
      GLL(vSrc + vo,              &Vs[0][w * 512]);
      GLL(vSrc + vo + 65536,      &Vs[0][w * 512 + 2048]);
      GLL(vSrc + vo + 64,         &Vs[1][w * 512]);
      GLL(vSrc + vo + 64 + 65536, &Vs[1][w * 512 + 2048]);
    }
    if (i + 2 < 16) {   // K(i+2) -> Ks[p] (just freed)
      const size_t ko = (size_t)(2 * i + 4) * 4096;
      GLL(kSrc + ko,        &Ks[p][0][w * 512]);
      GLL(kSrc + ko + 2048, &Ks[p][0][w * 512 + 2048]);
      GLL(kSrc + ko + 4096, &Ks[p][1][w * 512]);
      GLL(kSrc + ko + 6144, &Ks[p][1][w * 512 + 2048]);
    }
  }

  // combine halves (static shift => additive partials)
  float* scr = (float*)&Ks[0][0][0];
  const int sidA = (qg * 2 + 0) * 64 + l;
  const int sidB = (qg * 2 + 1) * 64 + l;
  if (half == 1) {
#pragma unroll
    for (int dt = 0; dt < 4; ++dt)
#pragma unroll
      for (int r = 0; r < 4; ++r) {
        scr[sidA * 17 + dt * 4 + r] = oaccA[dt][r];
        scr[sidB * 17 + dt * 4 + r] = oaccB[dt][r];
      }
    scr[sidA * 17 + 16] = laccA[0];
    scr[sidB * 17 + 16] = laccB[0];
  }
  __syncthreads();
  if (half == 1) return;
#pragma unroll
  for (int dt = 0; dt < 4; ++dt)
#pragma unroll
    for (int r = 0; r < 4; ++r) {
      oaccA[dt][r] += scr[sidA * 17 + dt * 4 + r];
      oaccB[dt][r] += scr[sidB * 17 + dt * 4 + r];
    }
  const float invA = 1.f / (laccA[0] + scr[sidA * 17 + 16]);
  const float invB = 1.f / (laccB[0] + scr[sidB * 17 + 16]);

  const int b = bh / NH, h = bh % NH;
  const int qA = q0 + qg * 32 + lr;
  size_t obA = (size_t)(b * SEQ + qA) * DIM + h * DH + 4 * lg;
  size_t obB = (size_t)(b * SEQ + qA + 16) * DIM + h * DH + 4 * lg;
#pragma unroll
  for (int dt = 0; dt < 4; ++dt) {
    ushort4 oA, oB;
    oA.x = f2bf(oaccA[dt][0] * invA); oA.y = f2bf(oaccA[dt][1] * invA);
    oA.z = f2bf(oaccA[dt][2] * invA); oA.w = f2bf(oaccA[dt][3] * invA);
    oB.x = f2bf(oaccB[dt][0] * invB); oB.y = f2bf(oaccB[dt][1] * invB);
    oB.z = f2bf(oaccB[dt][2] * invB); oB.w = f2bf(oaccB[dt][3] * invB);
    *(ushort4*)(Ob + obA + 16 * dt) = oA;
    *(ushort4*)(Ob + obB + 16 * dt) = oB;
  }
}

extern "C" void kernel_launch(void* const* d_in, const int* in_sizes, int n_in,
                              void* d_out, int out_size, void* d_ws, size_t ws_size,
                              hipStream_t stream) {
  const float* x      = (const float*)d_in[0];
  const float* pos    = (const float*)d_in[1];
  const float* qkv_w  = (const float*)d_in[2];
  const float* proj_w = (const float*)d_in[3];
  const float* proj_b = (const float*)d_in[4];
  const float* qn_w   = (const float*)d_in[5];
  const float* kn_w   = (const float*)d_in[6];
  char* ws = (char*)d_ws;
  u16*    xb    = (u16*)(ws + 0);          // 6291456
  u16*    wqkv  = (u16*)(ws + 6291456);    // 3538944
  u16*    wproj = (u16*)(ws + 9830400);    // 1179648
  float2* tab   = (float2*)(ws + 11010048);// 1048576
  u16*    Qb    = (u16*)(ws + 12058624);   // 6291456
  u16*    Kb    = (u16*)(ws + 18350080);   // 6291456
  u16*    Vtb   = (u16*)(ws + 24641536);   // 6291456
  u16*    Ob    = (u16*)(ws + 30932992);   // 6291456 -> total 37224448
  float* out = (float*)d_out;

  const int na4 = TOK * DIM / 4, nb4 = QKVN * DIM / 4, nc4 = DIM * DIM / 4;
  const int ntot = na4 + nb4 + nc4 + TOK * 32;
  conv_all<<<(ntot + 255) / 256, 256, 0, stream>>>(
      x, xb, na4, qkv_w, wqkv, nb4, proj_w, wproj, nc4, pos, tab);

  dim3 g1(TOK / 128, QKVN / 128);
  gemm_qkv<<<g1, 512, 0, stream>>>(xb, wqkv, qn_w, kn_w, tab, Qb, Kb, Vtb);

  attn<<<SEQ / 64 * BATCH * NH, 256, 0, stream>>>(Qb, Kb, Vtb, Ob);

  dim3 g3(TOK / 64, DIM / 64);
  gemm64<<<g3, 256, 0, stream>>>(Ob, wproj, out, proj_b, TOK, DIM, DIM);
}

// Round 11
// 88.622 us; speedup vs baseline: 1.3050x; 1.0143x over previous
//
#include <hip/hip_runtime.h>
#include <hip/hip_bf16.h>
#include <math.h>

#define DIM 768
#define NH 12
#define DH 64
#define SEQ 2048
#define BATCH 2
#define TOK (BATCH*SEQ)   // 4096
#define QKVN (3*DIM)      // 2304

typedef __attribute__((ext_vector_type(8))) short bf16x8;
typedef __attribute__((ext_vector_type(4))) float f32x4;
typedef __attribute__((ext_vector_type(2))) unsigned int u32x2;
typedef unsigned short u16;

#define VM0 asm volatile("s_waitcnt vmcnt(0)" ::: "memory")
#define VM3 asm volatile("s_waitcnt vmcnt(3)" ::: "memory")
#define VM4 asm volatile("s_waitcnt vmcnt(4)" ::: "memory")
#define LGKM0 asm volatile("s_waitcnt lgkmcnt(0)" ::: "memory")
#define BAR() __builtin_amdgcn_s_barrier()

__device__ inline u16 f2bf(float f) {
  union { float f; unsigned u; } v; v.f = f;
  unsigned u = v.u;
  u += 0x7fffu + ((u >> 16) & 1u);   // round-to-nearest-even
  return (u16)(u >> 16);
}

__device__ inline int pkbf(float a, float b) {   // packed bf16 pair (RNE)
  __hip_bfloat162 h = __float22bfloat162_rn(make_float2(a, b));
  int r; __builtin_memcpy(&r, &h, 4); return r;
}

// One launch: convert x, qkv_w, proj_w to bf16 AND build the rope cos/sin table.
__global__ void conv_all(const float* __restrict__ a, u16* __restrict__ ao, int na4,
                         const float* __restrict__ b, u16* __restrict__ bo, int nb4,
                         const float* __restrict__ c, u16* __restrict__ co, int nc4,
                         const float* __restrict__ pos, float2* __restrict__ tab) {
  int i4 = blockIdx.x * blockDim.x + threadIdx.x;
  const int nconv = na4 + nb4 + nc4;
  if (i4 < nconv) {
    const float* src; u16* dst; int off;
    if (i4 < na4)            { src = a; dst = ao; off = i4; }
    else if (i4 < na4 + nb4) { src = b; dst = bo; off = i4 - na4; }
    else                     { src = c; dst = co; off = i4 - na4 - nb4; }
    float4 v = ((const float4*)src)[off];
    ushort4 o;
    o.x = f2bf(v.x); o.y = f2bf(v.y); o.z = f2bf(v.z); o.w = f2bf(v.w);
    ((ushort4*)dst)[off] = o;
    return;
  }
  int e = i4 - nconv;                 // rope table: 4096*32 entries
  if (e >= TOK * 32) return;
  int t = e >> 5, p = e & 31;
  float cs = 1.f, sn = 0.f;
  if (p < 30) {
    int axis = p / 10, fi = p % 10;
    float freq = exp2f(-(float)fi * 1.3287712379549449f); // log2(10000)/10
    float ang = pos[t * 3 + axis] * freq;
    cs = cosf(ang); sn = sinf(ang);
  }
  tab[e] = make_float2(cs, sn);
}

#define GLL(g, s) __builtin_amdgcn_global_load_lds((const __attribute__((address_space(1))) void*)(g), (__attribute__((address_space(3))) void*)(s), 16, 0, 0)

// Proj GEMM: C = A * W^T + bias. 64x64 tile, BK=64, XOR-swizzled LDS.
__global__ __launch_bounds__(256, 4) void gemm64(
    const u16* __restrict__ A, const u16* __restrict__ W,
    float* __restrict__ C, const float* __restrict__ bias,
    int M, int Nn, int K)
{
  __shared__ u16 As[2][64 * 64];
  __shared__ u16 Bs[2][64 * 64];
  const int t = threadIdx.x;
  const int w = t >> 6, l = t & 63;
  const int lr = l & 15, lg = l >> 4;
  const int wr = w >> 1, wc = w & 1;
  const int m0 = blockIdx.x * 64;
  const int n0 = blockIdx.y * 64;
  f32x4 acc[2][2] = {};
  const int srow = t >> 3;                      // 0..31
  const int scol = (((t & 7) ^ (srow & 7)) * 8);
  const u16* aSrc = A + (size_t)(m0 + srow) * K + scol;
  const u16* bSrc = W + (size_t)(n0 + srow) * K + scol;
  const size_t r32 = (size_t)32 * K;
  const int sw = lr & 7;
  const int NT = K / 64;

  GLL(aSrc,       &As[0][w * 512]);
  GLL(aSrc + r32, &As[0][2048 + w * 512]);
  GLL(bSrc,       &Bs[0][w * 512]);
  GLL(bSrc + r32, &Bs[0][2048 + w * 512]);

  for (int kt = 0; kt < NT; ++kt) {
    const int cur = kt & 1;
    if (kt + 1 < NT) {
      const int k0 = (kt + 1) * 64;
      GLL(aSrc + k0,       &As[cur ^ 1][w * 512]);
      GLL(aSrc + r32 + k0, &As[cur ^ 1][2048 + w * 512]);
      GLL(bSrc + k0,       &Bs[cur ^ 1][w * 512]);
      GLL(bSrc + r32 + k0, &Bs[cur ^ 1][2048 + w * 512]);
      VM4;
    } else {
      VM0;
    }
    BAR();
#pragma unroll
    for (int kk = 0; kk < 2; ++kk) {
      bf16x8 af[2], bff[2];
#pragma unroll
      for (int mi = 0; mi < 2; ++mi)
        af[mi] = *(const bf16x8*)(&As[cur][0] + (wr * 32 + mi * 16 + lr) * 64 + (((kk * 4 + lg) ^ sw) * 8));
#pragma unroll
      for (int ni = 0; ni < 2; ++ni)
        bff[ni] = *(const bf16x8*)(&Bs[cur][0] + (wc * 32 + ni * 16 + lr) * 64 + (((kk * 4 + lg) ^ sw) * 8));
#pragma unroll
      for (int mi = 0; mi < 2; ++mi)
#pragma unroll
        for (int ni = 0; ni < 2; ++ni)
          acc[mi][ni] = __builtin_amdgcn_mfma_f32_16x16x32_bf16(af[mi], bff[ni], acc[mi][ni], 0, 0, 0);
    }
    LGKM0;
    BAR();
  }

#pragma unroll
  for (int mi = 0; mi < 2; ++mi)
#pragma unroll
    for (int ni = 0; ni < 2; ++ni)
#pragma unroll
      for (int r = 0; r < 4; ++r) {
        int row = m0 + wr * 32 + mi * 16 + lg * 4 + r;
        int col = n0 + wc * 32 + ni * 16 + lr;
        C[(size_t)row * Nn + col] = acc[mi][ni][r] + bias[col];
      }
}

// QKV GEMM + fused RMSNorm/RoPE/layout. 128M x 64N tile, 8 waves of 16x64
// (each wave owns one full (type,head) chunk). BK=64, 48KB LDS -> 3 blk/CU
// = 24 waves/CU. Grid 32x36 = 1152 blocks.
__global__ __launch_bounds__(512, 6) void gemm_qkv(
    const u16* __restrict__ A, const u16* __restrict__ W,
    const float* __restrict__ qn_w, const float* __restrict__ kn_w,
    const float2* __restrict__ tab,
    u16* __restrict__ Qb, u16* __restrict__ Kb, u16* __restrict__ Vtb)
{
  __shared__ u16 As[2][128 * 64];   // 16KB
  __shared__ u16 Bs[2][64 * 64];    // 8KB
  const int K = DIM;
  const int t = threadIdx.x;
  const int w = t >> 6, l = t & 63;
  const int lr = l & 15, lg = l >> 4;
  const int m0 = blockIdx.x * 128;
  const int n0 = blockIdx.y * 64;
  f32x4 acc[4] = {};
  const int srow = t >> 3;                      // 0..63
  const int scol = (((t & 7) ^ (srow & 7)) * 8);
  const u16* aSrc = A + (size_t)(m0 + srow) * K + scol;
  const u16* bSrc = W + (size_t)(n0 + srow) * K + scol;
  const size_t r64 = (size_t)64 * K;
  const int sw = lr & 7;
  const int NT = K / 64;

  GLL(aSrc,       &As[0][w * 512]);
  GLL(aSrc + r64, &As[0][4096 + w * 512]);
  GLL(bSrc,       &Bs[0][w * 512]);

  for (int kt = 0; kt < NT; ++kt) {
    const int cur = kt & 1;
    if (kt + 1 < NT) {
      const int k0 = (kt + 1) * 64;
      GLL(aSrc + k0,       &As[cur ^ 1][w * 512]);
      GLL(aSrc + r64 + k0, &As[cur ^ 1][4096 + w * 512]);
      GLL(bSrc + k0,       &Bs[cur ^ 1][w * 512]);
      VM3;
    } else {
      VM0;
    }
    BAR();
#pragma unroll
    for (int kk = 0; kk < 2; ++kk) {
      bf16x8 af = *(const bf16x8*)(&As[cur][0] + (w * 16 + lr) * 64 + (((kk * 4 + lg) ^ sw) * 8));
      bf16x8 bff[4];
#pragma unroll
      for (int ni = 0; ni < 4; ++ni)
        bff[ni] = *(const bf16x8*)(&Bs[cur][0] + (ni * 16 + lr) * 64 + (((kk * 4 + lg) ^ sw) * 8));
#pragma unroll
      for (int ni = 0; ni < 4; ++ni)
        acc[ni] = __builtin_amdgcn_mfma_f32_16x16x32_bf16(af, bff[ni], acc[ni], 0, 0, 0);
    }
    LGKM0;
    BAR();
  }

  // ---- fused epilogue ----
  const int chunk = n0 >> 6;               // 0..35 over [3 types][12 heads]
  const int tt = chunk / 12;               // 0=q 1=k 2=v
  const int h  = chunk % 12;
  const int bB = m0 >> 11;                 // batch (block-const)
  const int bh = bB * NH + h;

  if (tt == 2) {
    const int nbase = (m0 + w * 16 + lg * 4) & 2047;
#pragma unroll
    for (int ni = 0; ni < 4; ++ni) {
      const int d = ni * 16 + lr;
      ushort4 o;
      o.x = f2bf(acc[ni][0]); o.y = f2bf(acc[ni][1]);
      o.z = f2bf(acc[ni][2]); o.w = f2bf(acc[ni][3]);
      *(ushort4*)(Vtb + ((size_t)bh * DH + d) * SEQ + nbase) = o;
    }
  } else {
    const float* wv = (tt == 0 ? qn_w : kn_w);
    const float qs = (tt == 0 ? 0.125f * 1.4426950408889634f : 1.f);
    float wgt[4];
#pragma unroll
    for (int ni = 0; ni < 4; ++ni) wgt[ni] = wv[ni * 16 + lr];
    u16* outp = (tt == 0 ? Qb : Kb) + (size_t)bh * SEQ * DH;
#pragma unroll
    for (int r = 0; r < 4; ++r) {
      float ss = 0.f;
#pragma unroll
      for (int ni = 0; ni < 4; ++ni) ss += acc[ni][r] * acc[ni][r];
      ss += __shfl_xor(ss, 1, 64);
      ss += __shfl_xor(ss, 2, 64);
      ss += __shfl_xor(ss, 4, 64);
      ss += __shfl_xor(ss, 8, 64);
      const float rms = rsqrtf(ss * (1.f / 64.f) + 1e-6f);
      const int trow = m0 + w * 16 + lg * 4 + r;
      const float2* tl = tab + trow * 32;
      u16* rowp = outp + (size_t)(trow & 2047) * DH;
#pragma unroll
      for (int ni = 0; ni < 4; ++ni) {
        const int d = ni * 16 + lr;
        float v = acc[ni][r] * rms * wgt[ni];
        float vp = __shfl_xor(v, 1, 64);
        float2 cssn = tl[ni * 8 + (lr >> 1)];
        float sgn = (d & 1) ? cssn.y : -cssn.y;
        rowp[d] = f2bf((v * cssn.x + vp * sgn) * qs);
      }
    }
  }
}

// Flash attention v5: v4 structure with corrected counted-vmcnt schedule:
//   top: K(i) visible (prev beta's VM0+BAR)
//   QK + softmax (V(i), K(i+1) in flight)
//   alpha: VM4 (V(i) landed, K(i+1) STAYS in flight) + BAR
//   PV burst
//   beta: LGKM0 + VM0 (K(i+1) landed, flight=alpha+PV) + BAR; issue V(i+1),K(i+2)
__global__ __launch_bounds__(256, 3) void attn(
    const u16* __restrict__ Qb, const u16* __restrict__ Kb,
    const u16* __restrict__ Vtb, u16* __restrict__ Ob)
{
  __shared__ u16 Ks[2][2][64 * 64];   // [pair dbuf][tile-in-pair]
  __shared__ u16 Vs[2][64 * 64];      // [tile-in-pair]
  const int tid = threadIdx.x;
  const int w = tid >> 6, l = tid & 63;
  const int lr = l & 15, lg = l >> 4;
  const int qg = w & 1, half = w >> 1;
  const int wg = blockIdx.x;
  const int swz = (wg & 7) * 96 + (wg >> 3);   // bijective, 768 % 8 == 0
  const int bh = swz >> 5;
  const int q0 = (swz & 31) * 64;
  const u16* Qp = Qb + (size_t)bh * SEQ * DH;
  const u16* Kp = Kb + (size_t)bh * SEQ * DH;
  const u16* Vp = Vtb + (size_t)bh * DH * SEQ;

  const int qrA = q0 + qg * 32 + lr;
  const bf16x8 bq0a = *(const bf16x8*)(Qp + (size_t)qrA * DH + 8 * lg);
  const bf16x8 bq1a = *(const bf16x8*)(Qp + (size_t)qrA * DH + 32 + 8 * lg);
  const bf16x8 bq0b = *(const bf16x8*)(Qp + (size_t)(qrA + 16) * DH + 8 * lg);
  const bf16x8 bq1b = *(const bf16x8*)(Qp + (size_t)(qrA + 16) * DH + 32 + 8 * lg);

  const int srow = tid >> 3;                  // 0..31
  const int sc16 = (tid & 7) ^ (srow & 7);
  const u16* kSrc = Kp + (size_t)srow * DH + sc16 * 8;    // + kt*4096
  const u16* vSrc = Vp + (size_t)srow * SEQ + sc16 * 8;   // + kt*64

  const int frow = (lr & 3) | ((lr & 4) << 1) | ((lr & 8) >> 1);
  const int ksw = frow & 7;
  const int vsw = lr & 7;

  bf16x8 vone;
#pragma unroll
  for (int j = 0; j < 8; ++j) vone[j] = (short)0x3F80;

  f32x4 oaccA[4] = {}, oaccB[4] = {};
  f32x4 laccA = {}, laccB = {};

  // prologue: K(0); drain; barrier; then V(0), K(1) in flight
  GLL(kSrc,          &Ks[0][0][w * 512]);
  GLL(kSrc + 2048,   &Ks[0][0][w * 512 + 2048]);
  GLL(kSrc + 4096,   &Ks[0][1][w * 512]);
  GLL(kSrc + 6144,   &Ks[0][1][w * 512 + 2048]);
  VM0;
  BAR();
  GLL(vSrc,              &Vs[0][w * 512]);
  GLL(vSrc + 65536,      &Vs[0][w * 512 + 2048]);
  GLL(vSrc + 64,         &Vs[1][w * 512]);
  GLL(vSrc + 64 + 65536, &Vs[1][w * 512 + 2048]);
  GLL(kSrc + 8192,   &Ks[1][0][w * 512]);
  GLL(kSrc + 10240,  &Ks[1][0][w * 512 + 2048]);
  GLL(kSrc + 12288,  &Ks[1][1][w * 512]);
  GLL(kSrc + 14336,  &Ks[1][1][w * 512 + 2048]);

  for (int i = 0; i < 16; ++i) {
    const int p = i & 1;
    const u16* Kt = &Ks[p][half][0];
    const u16* Vt = &Vs[half][0];

    // QK: 16 MFMA (K(i) visible since previous beta)
    f32x4 paccA[4] = {}, paccB[4] = {};
    __builtin_amdgcn_s_setprio(1);
#pragma unroll
    for (int c = 0; c < 4; ++c) {
      const int rbase = (16 * c + frow) * 64;
      bf16x8 ka = *(const bf16x8*)(Kt + rbase + ((lg ^ ksw) * 8));
      bf16x8 kb = *(const bf16x8*)(Kt + rbase + (((4 + lg) ^ ksw) * 8));
      paccA[c] = __builtin_amdgcn_mfma_f32_16x16x32_bf16(ka, bq0a, paccA[c], 0, 0, 0);
      paccA[c] = __builtin_amdgcn_mfma_f32_16x16x32_bf16(kb, bq1a, paccA[c], 0, 0, 0);
      paccB[c] = __builtin_amdgcn_mfma_f32_16x16x32_bf16(ka, bq0b, paccB[c], 0, 0, 0);
      paccB[c] = __builtin_amdgcn_mfma_f32_16x16x32_bf16(kb, bq1b, paccB[c], 0, 0, 0);
    }
    __builtin_amdgcn_s_setprio(0);

    // softmax fully in-register (overlaps V(i)/K(i+1) landing)
    union { unsigned d[4]; bf16x8 v; } puA[2], puB[2];
#pragma unroll
    for (int g = 0; g < 2; ++g) {
      const int clo = 2 * g, chi = 2 * g + 1;
      float eA[8], eB[8];
#pragma unroll
      for (int r = 0; r < 4; ++r) {
        eA[r]     = __builtin_amdgcn_exp2f(paccA[clo][r] - 12.f);
        eA[4 + r] = __builtin_amdgcn_exp2f(paccA[chi][r] - 12.f);
        eB[r]     = __builtin_amdgcn_exp2f(paccB[clo][r] - 12.f);
        eB[4 + r] = __builtin_amdgcn_exp2f(paccB[chi][r] - 12.f);
      }
      u32x2 a0 = __builtin_amdgcn_permlane32_swap((unsigned)pkbf(eA[0], eA[1]),
                                                  (unsigned)pkbf(eA[4], eA[5]), false, false);
      u32x2 a1 = __builtin_amdgcn_permlane32_swap((unsigned)pkbf(eA[2], eA[3]),
                                                  (unsigned)pkbf(eA[6], eA[7]), false, false);
      u32x2 b0 = __builtin_amdgcn_permlane32_swap((unsigned)pkbf(eB[0], eB[1]),
                                                  (unsigned)pkbf(eB[4], eB[5]), false, false);
      u32x2 b1 = __builtin_amdgcn_permlane32_swap((unsigned)pkbf(eB[2], eB[3]),
                                                  (unsigned)pkbf(eB[6], eB[7]), false, false);
      puA[g].d[0] = a0[0]; puA[g].d[1] = a1[0]; puA[g].d[2] = a0[1]; puA[g].d[3] = a1[1];
      puB[g].d[0] = b0[0]; puB[g].d[1] = b1[0]; puB[g].d[2] = b0[1]; puB[g].d[3] = b1[1];
    }

    if (i < 15) { VM4; } else { VM0; }   // alpha: V(i) landed, K(i+1) flies on
    BAR();

    // PV: pure MFMA burst
    __builtin_amdgcn_s_setprio(1);
#pragma unroll
    for (int g = 0; g < 2; ++g) {
#pragma unroll
      for (int dt = 0; dt < 4; ++dt) {
        bf16x8 va = *(const bf16x8*)(Vt + (16 * dt + lr) * 64 + (((4 * g + lg) ^ vsw) * 8));
        oaccA[dt] = __builtin_amdgcn_mfma_f32_16x16x32_bf16(va, puA[g].v, oaccA[dt], 0, 0, 0);
        oaccB[dt] = __builtin_amdgcn_mfma_f32_16x16x32_bf16(va, puB[g].v, oaccB[dt], 0, 0, 0);
      }
      laccA = __builtin_amdgcn_mfma_f32_16x16x32_bf16(vone, puA[g].v, laccA, 0, 0, 0);
      laccB = __builtin_amdgcn_mfma_f32_16x16x32_bf16(vone, puB[g].v, laccB, 0, 0, 0);
    }
    __builtin_amdgcn_s_setprio(0);

    LGKM0;  // my LDS reads done
    VM0;    // beta: K(i+1) landed (flight = alpha + PV)
    BAR();  // buffers free + K(i+1) visible block-wide

    if (i + 1 < 16) {   // V(i+1) -> Vs (flight = next QK+softmax)
      const size_t vo = (size_t)(2 * i + 2) * 64;
      GLL(vSrc + vo,              &Vs[0][w * 512]);
      GLL(vSrc + vo + 65536,      &Vs[0][w * 512 + 2048]);
      GLL(vSrc + vo + 64,         &Vs[1][w * 512]);
      GLL(vSrc + vo + 64 + 65536, &Vs[1][w * 512 + 2048]);
    }
    if (i + 2 < 16) {   // K(i+2) -> Ks[p] (just freed)
      const size_t ko = (size_t)(2 * i + 4) * 4096;
      GLL(kSrc + ko,        &Ks[p][0][w * 512]);
      GLL(kSrc + ko + 2048, &Ks[p][0][w * 512 + 2048]);
      GLL(kSrc + ko + 4096, &Ks[p][1][w * 512]);
      GLL(kSrc + ko + 6144, &Ks[p][1][w * 512 + 2048]);
    }
  }

  // combine halves (static shift => additive partials)
  float* scr = (float*)&Ks[0][0][0];
  const int sidA = (qg * 2 + 0) * 64 + l;
  const int sidB = (qg * 2 + 1) * 64 + l;
  if (half == 1) {
#pragma unroll
    for (int dt = 0; dt < 4; ++dt)
#pragma unroll
      for (int r = 0; r < 4; ++r) {
        scr[sidA * 17 + dt * 4 + r] = oaccA[dt][r];
        scr[sidB * 17 + dt * 4 + r] = oaccB[dt][r];
      }
    scr[sidA * 17 + 16] = laccA[0];
    scr[sidB * 17 + 16] = laccB[0];
  }
  __syncthreads();
  if (half == 1) return;
#pragma unroll
  for (int dt = 0; dt < 4; ++dt)
#pragma unroll
    for (int r = 0; r < 4; ++r) {
      oaccA[dt][r] += scr[sidA * 17 + dt * 4 + r];
      oaccB[dt][r] += scr[sidB * 17 + dt * 4 + r];
    }
  const float invA = 1.f / (laccA[0] + scr[sidA * 17 + 16]);
  const float invB = 1.f / (laccB[0] + scr[sidB * 17 + 16]);

  const int b = bh / NH, h = bh % NH;
  const int qA = q0 + qg * 32 + lr;
  size_t obA = (size_t)(b * SEQ + qA) * DIM + h * DH + 4 * lg;
  size_t obB = (size_t)(b * SEQ + qA + 16) * DIM + h * DH + 4 * lg;
#pragma unroll
  for (int dt = 0; dt < 4; ++dt) {
    ushort4 oA, oB;
    oA.x = f2bf(oaccA[dt][0] * invA); oA.y = f2bf(oaccA[dt][1] * invA);
    oA.z = f2bf(oaccA[dt][2] * invA); oA.w = f2bf(oaccA[dt][3] * invA);
    oB.x = f2bf(oaccB[dt][0] * invB); oB.y = f2bf(oaccB[dt][1] * invB);
    oB.z = f2bf(oaccB[dt][2] * invB); oB.w = f2bf(oaccB[dt][3] * invB);
    *(ushort4*)(Ob + obA + 16 * dt) = oA;
    *(ushort4*)(Ob + obB + 16 * dt) = oB;
  }
}

extern "C" void kernel_launch(void* const* d_in, const int* in_sizes, int n_in,
                              void* d_out, int out_size, void* d_ws, size_t ws_size,
                              hipStream_t stream) {
  const float* x      = (const float*)d_in[0];
  const float* pos    = (const float*)d_in[1];
  const float* qkv_w  = (const float*)d_in[2];
  const float* proj_w = (const float*)d_in[3];
  const float* proj_b = (const float*)d_in[4];
  const float* qn_w   = (const float*)d_in[5];
  const float* kn_w   = (const float*)d_in[6];
  char* ws = (char*)d_ws;
  u16*    xb    = (u16*)(ws + 0);          // 6291456
  u16*    wqkv  = (u16*)(ws + 6291456);    // 3538944
  u16*    wproj = (u16*)(ws + 9830400);    // 1179648
  float2* tab   = (float2*)(ws + 11010048);// 1048576
  u16*    Qb    = (u16*)(ws + 12058624);   // 6291456
  u16*    Kb    = (u16*)(ws + 18350080);   // 6291456
  u16*    Vtb   = (u16*)(ws + 24641536);   // 6291456
  u16*    Ob    = (u16*)(ws + 30932992);   // 6291456 -> total 37224448
  float* out = (float*)d_out;

  const int na4 = TOK * DIM / 4, nb4 = QKVN * DIM / 4, nc4 = DIM * DIM / 4;
  const int ntot = na4 + nb4 + nc4 + TOK * 32;
  conv_all<<<(ntot + 255) / 256, 256, 0, stream>>>(
      x, xb, na4, qkv_w, wqkv, nb4, proj_w, wproj, nc4, pos, tab);

  dim3 g1(TOK / 128, QKVN / 64);
  gemm_qkv<<<g1, 512, 0, stream>>>(xb, wqkv, qn_w, kn_w, tab, Qb, Kb, Vtb);

  attn<<<SEQ / 64 * BATCH * NH, 256, 0, stream>>>(Qb, Kb, Vtb, Ob);

  dim3 g3(TOK / 64, DIM / 64);
  gemm64<<<g3, 256, 0, stream>>>(Ob, wproj, out, proj_b, TOK, DIM, DIM);
}